// Round 1
// baseline (2038.010 us; speedup 1.0000x reference)
//
#include <hip/hip_runtime.h>

#define CH 128
#define N_REL 8
#define OUT_CH 16
#define NEG_SLOPE 0.2f

// ---------- helpers ----------
__device__ __forceinline__ unsigned enc_f(float f) {
    unsigned u = __float_as_uint(f);
    return (u & 0x80000000u) ? ~u : (u | 0x80000000u);
}
__device__ __forceinline__ float dec_f(unsigned u) {
    return (u & 0x80000000u) ? __uint_as_float(u & 0x7fffffffu) : __uint_as_float(~u);
}
__device__ __forceinline__ unsigned short f2bf(float f) {  // RTN-even f32->bf16
    unsigned u = __float_as_uint(f);
    return (unsigned short)((u + 0x7fffu + ((u >> 16) & 1u)) >> 16);
}
__device__ __forceinline__ float bf2f(unsigned short h) {
    return __uint_as_float(((unsigned)h) << 16);
}

// ---------- wq[r] = W[r] @ q, wk[r] = W[r] @ k  (tiny) ----------
__global__ void k_wqk(const float* __restrict__ W, const float* __restrict__ qv,
                      const float* __restrict__ kv, float* __restrict__ wq,
                      float* __restrict__ wk) {
    int r = blockIdx.x;       // N_REL
    int i = threadIdx.x;      // CH
    const float* row = W + ((size_t)r * CH + i) * CH;
    float aq = 0.f, ak = 0.f;
    for (int o = 0; o < CH; ++o) { float w = row[o]; aq += w * qv[o]; ak += w * kv[o]; }
    wq[r * CH + i] = aq;
    wk[r * CH + i] = ak;
}

// ---------- XW[r] = X @ W[r]  (fp32 compute, bf16 store) ----------
// tile: 64 rows x 128 cols, K=128 in 4 chunks of 32. 256 thr, micro 8x4.
__global__ __launch_bounds__(256) void k_gemm(const float* __restrict__ X,
                                              const float* __restrict__ W,
                                              unsigned short* __restrict__ XW,
                                              int n_nodes) {
    __shared__ float Xs[64][132];
    __shared__ float Ws[32][128];
    const int r = blockIdx.y;
    const int n0 = blockIdx.x * 64;
    const int tid = threadIdx.x;

    // stage X tile (zero-pad tail rows)
    for (int i = 0; i < 8; ++i) {
        int idx = tid + i * 256;           // 0..2047 float4s
        int row = idx >> 5;
        int c4 = (idx & 31) << 2;
        float4 v = make_float4(0.f, 0.f, 0.f, 0.f);
        int gr = n0 + row;
        if (gr < n_nodes) v = *(const float4*)(X + (size_t)gr * CH + c4);
        *(float4*)(&Xs[row][c4]) = v;
    }

    float acc[8][4] = {};
    const int tx = tid & 31, ty = tid >> 5;
    const int c0 = tx << 2;
    const float* Wr = W + (size_t)r * CH * CH;

    for (int kt = 0; kt < CH; kt += 32) {
        __syncthreads();
        for (int i = 0; i < 4; ++i) {
            int idx = tid + i * 256;       // 0..1023 float4s
            int k = idx >> 5;
            int c4 = (idx & 31) << 2;
            *(float4*)(&Ws[k][c4]) = *(const float4*)(Wr + (size_t)(kt + k) * CH + c4);
        }
        __syncthreads();
        #pragma unroll
        for (int kk = 0; kk < 32; kk += 4) {
            float4 w0 = *(const float4*)(&Ws[kk + 0][c0]);
            float4 w1 = *(const float4*)(&Ws[kk + 1][c0]);
            float4 w2 = *(const float4*)(&Ws[kk + 2][c0]);
            float4 w3 = *(const float4*)(&Ws[kk + 3][c0]);
            #pragma unroll
            for (int j = 0; j < 8; ++j) {
                float4 xv = *(const float4*)(&Xs[ty * 8 + j][kt + kk]);
                acc[j][0] += xv.x * w0.x + xv.y * w1.x + xv.z * w2.x + xv.w * w3.x;
                acc[j][1] += xv.x * w0.y + xv.y * w1.y + xv.z * w2.y + xv.w * w3.y;
                acc[j][2] += xv.x * w0.z + xv.y * w1.z + xv.z * w2.z + xv.w * w3.z;
                acc[j][3] += xv.x * w0.w + xv.y * w1.w + xv.z * w2.w + xv.w * w3.w;
            }
        }
    }

    for (int j = 0; j < 8; ++j) {
        int gr = n0 + ty * 8 + j;
        if (gr < n_nodes) {
            ushort4 o;
            o.x = f2bf(acc[j][0]); o.y = f2bf(acc[j][1]);
            o.z = f2bf(acc[j][2]); o.w = f2bf(acc[j][3]);
            *(ushort4*)(XW + ((size_t)r * n_nodes + gr) * CH + c0) = o;
        }
    }
}

// ---------- sq[r][n] = x[n].wq[r], sk likewise (wave per node) ----------
__global__ __launch_bounds__(256) void k_sqsk(const float* __restrict__ X,
                                              const float* __restrict__ wq,
                                              const float* __restrict__ wk,
                                              float* __restrict__ sq,
                                              float* __restrict__ sk, int n_nodes) {
    int wave = (blockIdx.x * 256 + threadIdx.x) >> 6;
    int lane = threadIdx.x & 63;
    if (wave >= n_nodes) return;
    float x0 = X[(size_t)wave * CH + lane];
    float x1 = X[(size_t)wave * CH + 64 + lane];
    #pragma unroll
    for (int r = 0; r < N_REL; ++r) {
        float s1 = x0 * wq[r * CH + lane] + x1 * wq[r * CH + 64 + lane];
        float s2 = x0 * wk[r * CH + lane] + x1 * wk[r * CH + 64 + lane];
        #pragma unroll
        for (int off = 32; off; off >>= 1) {
            s1 += __shfl_xor(s1, off);
            s2 += __shfl_xor(s2, off);
        }
        if (lane == 0) { sq[r * n_nodes + wave] = s1; sk[r * n_nodes + wave] = s2; }
    }
}

// ---------- per-edge logits + segment max ----------
__global__ void k_edge_logit(const int* __restrict__ src, const int* __restrict__ dst,
                             const int* __restrict__ et, const float* __restrict__ sq,
                             const float* __restrict__ sk, float* __restrict__ a_e,
                             unsigned* __restrict__ amax, int n_edges, int n_nodes) {
    int e = blockIdx.x * 256 + threadIdx.x;
    if (e >= n_edges) return;
    int s = src[e], d = dst[e], t = et[e];
    float a = sq[t * n_nodes + d] + sk[t * n_nodes + s];
    a = a >= 0.f ? a : NEG_SLOPE * a;
    a_e[e] = a;
    atomicMax(amax + d, enc_f(a));
}

// ---------- per-edge exp + segment sum ----------
__global__ void k_edge_exp(const int* __restrict__ dst, const float* __restrict__ a_e,
                           const unsigned* __restrict__ amax, float* __restrict__ e_e,
                           float* __restrict__ denom, int n_edges) {
    int e = blockIdx.x * 256 + threadIdx.x;
    if (e >= n_edges) return;
    int d = dst[e];
    float ev = expf(a_e[e] - dec_f(amax[d]));
    e_e[e] = ev;
    atomicAdd(denom + d, ev);
}

// ---------- weighted scatter aggregation (wave per edge) ----------
__global__ __launch_bounds__(256) void k_edge_agg(const int* __restrict__ src,
                                                  const int* __restrict__ dst,
                                                  const int* __restrict__ et,
                                                  const float* __restrict__ e_e,
                                                  const float* __restrict__ denom,
                                                  const unsigned short* __restrict__ XW,
                                                  float* __restrict__ out,
                                                  int n_edges, int n_nodes) {
    int wid = (blockIdx.x * 256 + threadIdx.x) >> 6;
    int lane = threadIdx.x & 63;
    if (wid >= n_edges) return;
    int s = src[wid], d = dst[wid], t = et[wid];
    float alpha = e_e[wid] / denom[d];
    const unsigned short* row = XW + ((size_t)t * n_nodes + s) * CH;
    float* orow = out + (size_t)d * CH;
    unsigned v = *(const unsigned*)(row + lane * 2);
    float f0 = __uint_as_float(v << 16);
    float f1 = __uint_as_float(v & 0xffff0000u);
    atomicAdd(orow + lane * 2 + 0, alpha * f0);
    atomicAdd(orow + lane * 2 + 1, alpha * f1);
}

// ---------- bias + relu (in place) ----------
__global__ void k_bias_relu(float* __restrict__ h, const float* __restrict__ b, long total) {
    long i = (long)blockIdx.x * 256 + threadIdx.x;
    if (i >= total) return;
    float v = h[i] + b[i & (CH - 1)];
    h[i] = v > 0.f ? v : 0.f;
}

// ---------- column sum over nodes ----------
__global__ __launch_bounds__(256) void k_colsum(const float* __restrict__ h,
                                                float* __restrict__ sum, int n_nodes) {
    int c = threadIdx.x & 127;
    int half = threadIdx.x >> 7;
    float acc = 0.f;
    for (int row = blockIdx.x * 2 + half; row < n_nodes; row += gridDim.x * 2)
        acc += h[(size_t)row * CH + c];
    atomicAdd(sum + c, acc);
}

// ---------- head: mean -> 128x16 matvec -> log_softmax ----------
__global__ void k_head(const float* __restrict__ sum, const float* __restrict__ lw,
                       const float* __restrict__ lb, float* __restrict__ outp, int n_nodes) {
    __shared__ float mean[CH];
    int t = threadIdx.x;  // 128
    mean[t] = sum[t] / (float)n_nodes;
    __syncthreads();
    if (t < OUT_CH) {
        float g = lb[t];
        for (int i = 0; i < CH; ++i) g += mean[i] * lw[i * OUT_CH + t];
        float m = g;
        #pragma unroll
        for (int off = 8; off; off >>= 1) m = fmaxf(m, __shfl_xor(m, off, 16));
        float ex = expf(g - m);
        float se = ex;
        #pragma unroll
        for (int off = 8; off; off >>= 1) se += __shfl_xor(se, off, 16);
        outp[t] = g - m - logf(se);
    }
}

extern "C" void kernel_launch(void* const* d_in, const int* in_sizes, int n_in,
                              void* d_out, int out_size, void* d_ws, size_t ws_size,
                              hipStream_t stream) {
    const float* x  = (const float*)d_in[0];
    const float* W1 = (const float*)d_in[1];
    const float* q1 = (const float*)d_in[2];
    const float* k1 = (const float*)d_in[3];
    const float* b1 = (const float*)d_in[4];
    const float* W2 = (const float*)d_in[5];
    const float* q2 = (const float*)d_in[6];
    const float* k2 = (const float*)d_in[7];
    const float* b2 = (const float*)d_in[8];
    const float* lw = (const float*)d_in[9];
    const float* lb = (const float*)d_in[10];
    const int* ei   = (const int*)d_in[11];
    const int* etp  = (const int*)d_in[12];

    const int n  = in_sizes[0] / CH;
    const int ne = in_sizes[12];
    const int* esrc = ei;
    const int* edst = ei + ne;

    char* ws = (char*)d_ws;
    size_t off = 0;
    auto carve = [&](size_t bytes) -> char* {
        char* p = ws + off;
        off = (off + bytes + 255) & ~(size_t)255;
        return p;
    };
    unsigned short* xw = (unsigned short*)carve((size_t)N_REL * n * CH * 2);
    float* h1    = (float*)carve((size_t)n * CH * 4);
    float* h2    = (float*)carve((size_t)n * CH * 4);
    float* a_e   = (float*)carve((size_t)ne * 4);
    float* e_e   = (float*)carve((size_t)ne * 4);
    unsigned* amax = (unsigned*)carve((size_t)n * 4);
    float* denom = (float*)carve((size_t)n * 4);
    float* sq    = (float*)carve((size_t)N_REL * n * 4);
    float* sk    = (float*)carve((size_t)N_REL * n * 4);
    float* wq    = (float*)carve(N_REL * CH * 4);
    float* wk    = (float*)carve(N_REL * CH * 4);
    float* sum128 = (float*)carve(CH * 4);

    hipMemsetAsync(amax, 0, (size_t)n * 4, stream);
    hipMemsetAsync(denom, 0, (size_t)n * 4, stream);
    hipMemsetAsync(h1, 0, (size_t)n * CH * 4, stream);
    hipMemsetAsync(h2, 0, (size_t)n * CH * 4, stream);
    hipMemsetAsync(sum128, 0, CH * 4, stream);

    auto run_layer = [&](const float* X, const float* W, const float* qv,
                         const float* kv, const float* bv, float* hout) {
        k_wqk<<<N_REL, CH, 0, stream>>>(W, qv, kv, wq, wk);
        k_gemm<<<dim3((n + 63) / 64, N_REL), 256, 0, stream>>>(X, W, xw, n);
        k_sqsk<<<(n + 3) / 4, 256, 0, stream>>>(X, wq, wk, sq, sk, n);
        k_edge_logit<<<(ne + 255) / 256, 256, 0, stream>>>(esrc, edst, etp, sq, sk, a_e, amax, ne, n);
        k_edge_exp<<<(ne + 255) / 256, 256, 0, stream>>>(edst, a_e, amax, e_e, denom, ne);
        k_edge_agg<<<(ne + 3) / 4, 256, 0, stream>>>(esrc, edst, etp, e_e, denom, xw, hout, ne, n);
        long total = (long)n * CH;
        k_bias_relu<<<(unsigned)((total + 255) / 256), 256, 0, stream>>>(hout, bv, total);
    };

    run_layer(x, W1, q1, k1, b1, h1);
    hipMemsetAsync(amax, 0, (size_t)n * 4, stream);
    hipMemsetAsync(denom, 0, (size_t)n * 4, stream);
    run_layer(h1, W2, q2, k2, b2, h2);

    k_colsum<<<256, 256, 0, stream>>>(h2, sum128, n);
    k_head<<<1, CH, 0, stream>>>(sum128, lw, lb, (float*)d_out, n);
}

// Round 2
// 1102.551 us; speedup vs baseline: 1.8484x; 1.8484x over previous
//
#include <hip/hip_runtime.h>

#define CH 128
#define N_REL 8
#define OUT_CH 16
#define NEG_SLOPE 0.2f

// ---------- helpers ----------
__device__ __forceinline__ unsigned short f2bf(float f) {  // RTN-even f32->bf16
    unsigned u = __float_as_uint(f);
    return (unsigned short)((u + 0x7fffu + ((u >> 16) & 1u)) >> 16);
}

// ---------- wq[r] = W[r] @ q, wk[r] = W[r] @ k  (tiny) ----------
__global__ void k_wqk(const float* __restrict__ W, const float* __restrict__ qv,
                      const float* __restrict__ kv, float* __restrict__ wq,
                      float* __restrict__ wk) {
    int r = blockIdx.x;       // N_REL
    int i = threadIdx.x;      // CH
    const float* row = W + ((size_t)r * CH + i) * CH;
    float aq = 0.f, ak = 0.f;
    for (int o = 0; o < CH; ++o) { float w = row[o]; aq += w * qv[o]; ak += w * kv[o]; }
    wq[r * CH + i] = aq;
    wk[r * CH + i] = ak;
}

// ---------- XW[r] = X @ W[r]  (fp32 compute, bf16 store) ----------
__global__ __launch_bounds__(256) void k_gemm(const float* __restrict__ X,
                                              const float* __restrict__ W,
                                              unsigned short* __restrict__ XW,
                                              int n_nodes) {
    __shared__ float Xs[64][132];
    __shared__ float Ws[32][128];
    const int r = blockIdx.y;
    const int n0 = blockIdx.x * 64;
    const int tid = threadIdx.x;

    for (int i = 0; i < 8; ++i) {
        int idx = tid + i * 256;
        int row = idx >> 5;
        int c4 = (idx & 31) << 2;
        float4 v = make_float4(0.f, 0.f, 0.f, 0.f);
        int gr = n0 + row;
        if (gr < n_nodes) v = *(const float4*)(X + (size_t)gr * CH + c4);
        *(float4*)(&Xs[row][c4]) = v;
    }

    float acc[8][4] = {};
    const int tx = tid & 31, ty = tid >> 5;
    const int c0 = tx << 2;
    const float* Wr = W + (size_t)r * CH * CH;

    for (int kt = 0; kt < CH; kt += 32) {
        __syncthreads();
        for (int i = 0; i < 4; ++i) {
            int idx = tid + i * 256;
            int k = idx >> 5;
            int c4 = (idx & 31) << 2;
            *(float4*)(&Ws[k][c4]) = *(const float4*)(Wr + (size_t)(kt + k) * CH + c4);
        }
        __syncthreads();
        #pragma unroll
        for (int kk = 0; kk < 32; kk += 4) {
            float4 w0 = *(const float4*)(&Ws[kk + 0][c0]);
            float4 w1 = *(const float4*)(&Ws[kk + 1][c0]);
            float4 w2 = *(const float4*)(&Ws[kk + 2][c0]);
            float4 w3 = *(const float4*)(&Ws[kk + 3][c0]);
            #pragma unroll
            for (int j = 0; j < 8; ++j) {
                float4 xv = *(const float4*)(&Xs[ty * 8 + j][kt + kk]);
                acc[j][0] += xv.x * w0.x + xv.y * w1.x + xv.z * w2.x + xv.w * w3.x;
                acc[j][1] += xv.x * w0.y + xv.y * w1.y + xv.z * w2.y + xv.w * w3.y;
                acc[j][2] += xv.x * w0.z + xv.y * w1.z + xv.z * w2.z + xv.w * w3.z;
                acc[j][3] += xv.x * w0.w + xv.y * w1.w + xv.z * w2.w + xv.w * w3.w;
            }
        }
    }

    for (int j = 0; j < 8; ++j) {
        int gr = n0 + ty * 8 + j;
        if (gr < n_nodes) {
            ushort4 o;
            o.x = f2bf(acc[j][0]); o.y = f2bf(acc[j][1]);
            o.z = f2bf(acc[j][2]); o.w = f2bf(acc[j][3]);
            *(ushort4*)(XW + ((size_t)r * n_nodes + gr) * CH + c0) = o;
        }
    }
}

// ---------- sq[r][n] = x[n].wq[r], sk likewise (wave per node) ----------
__global__ __launch_bounds__(256) void k_sqsk(const float* __restrict__ X,
                                              const float* __restrict__ wq,
                                              const float* __restrict__ wk,
                                              float* __restrict__ sq,
                                              float* __restrict__ sk, int n_nodes) {
    int wave = (blockIdx.x * 256 + threadIdx.x) >> 6;
    int lane = threadIdx.x & 63;
    if (wave >= n_nodes) return;
    float x0 = X[(size_t)wave * CH + lane];
    float x1 = X[(size_t)wave * CH + 64 + lane];
    #pragma unroll
    for (int r = 0; r < N_REL; ++r) {
        float s1 = x0 * wq[r * CH + lane] + x1 * wq[r * CH + 64 + lane];
        float s2 = x0 * wk[r * CH + lane] + x1 * wk[r * CH + 64 + lane];
        #pragma unroll
        for (int off = 32; off; off >>= 1) {
            s1 += __shfl_xor(s1, off);
            s2 += __shfl_xor(s2, off);
        }
        if (lane == 0) { sq[r * n_nodes + wave] = s1; sk[r * n_nodes + wave] = s2; }
    }
}

// ---------- CSR build: histogram ----------
__global__ void k_hist(const int* __restrict__ dst, int* __restrict__ count, int ne) {
    int e = blockIdx.x * 256 + threadIdx.x;
    if (e >= ne) return;
    atomicAdd(count + dst[e], 1);
}

// ---------- CSR build: single-block exclusive scan (1024 threads) ----------
__global__ __launch_bounds__(1024) void k_scan(const int* __restrict__ count,
                                               int* __restrict__ rowptr,
                                               int* __restrict__ rowptr_work,
                                               int n_nodes) {
    __shared__ int wsum[16];
    __shared__ int wscan[16];
    __shared__ int carry_s;
    int tid = threadIdx.x, lane = tid & 63, w = tid >> 6;
    if (tid == 0) carry_s = 0;
    __syncthreads();
    for (int base = 0; base < n_nodes; base += 1024) {
        int i = base + tid;
        int v = (i < n_nodes) ? count[i] : 0;
        int s = v;
        #pragma unroll
        for (int off = 1; off < 64; off <<= 1) {
            int t = __shfl_up(s, off);
            if (lane >= off) s += t;
        }
        if (lane == 63) wsum[w] = s;
        __syncthreads();
        if (tid < 16) {
            int t = wsum[tid];
            #pragma unroll
            for (int off = 1; off < 16; off <<= 1) {
                int u = __shfl_up(t, off, 16);
                if ((lane & 15) >= off) t += u;
            }
            wscan[tid] = t;
        }
        __syncthreads();
        int wpref = (w == 0) ? 0 : wscan[w - 1];
        int excl = carry_s + wpref + s - v;
        if (i < n_nodes) { rowptr[i] = excl; rowptr_work[i] = excl; }
        __syncthreads();
        if (tid == 0) carry_s += wscan[15];
        __syncthreads();
    }
    if (tid == 0) rowptr[n_nodes] = carry_s;
}

// ---------- CSR build: scatter (src | et<<16 packed) ----------
__global__ void k_scatter(const int* __restrict__ src, const int* __restrict__ dst,
                          const int* __restrict__ et, int* __restrict__ rowptr_work,
                          int* __restrict__ pe, int ne) {
    int e = blockIdx.x * 256 + threadIdx.x;
    if (e >= ne) return;
    int pos = atomicAdd(rowptr_work + dst[e], 1);
    pe[pos] = (src[e] & 0xffff) | (et[e] << 16);
}

// ---------- fused per-node attention: logits->max->exp->gather-acc->bias->relu ----------
__global__ __launch_bounds__(256) void k_node_attn(
    const int* __restrict__ rowptr, const int* __restrict__ pe,
    const float* __restrict__ sq, const float* __restrict__ sk,
    const unsigned short* __restrict__ XW, const float* __restrict__ bias,
    float* __restrict__ out, int n_nodes) {
    int wid = (blockIdx.x * 256 + threadIdx.x) >> 6;
    int lane = threadIdx.x & 63;
    if (wid >= n_nodes) return;
    int r0 = rowptr[wid], r1 = rowptr[wid + 1];
    float acc0 = 0.f, acc1 = 0.f, denom = 0.f;

    if (r1 > r0) {
        // per-relation sq for this node, held lane r = sq[r][node]
        float sqv = (lane < N_REL) ? sq[lane * n_nodes + wid] : 0.f;

        // pass 1: global max over incoming edges
        float m = -1e30f;
        for (int c0 = r0; c0 < r1; c0 += 64) {
            int j = c0 + lane;
            float a = -1e30f;
            if (j < r1) {
                int p = pe[j];
                int s = p & 0xffff, t = p >> 16;
                float av = __shfl(sqv, t) + sk[t * n_nodes + s];
                a = av >= 0.f ? av : NEG_SLOPE * av;
            }
            m = fmaxf(m, a);
        }
        #pragma unroll
        for (int off = 32; off; off >>= 1) m = fmaxf(m, __shfl_xor(m, off));

        // pass 2: exp, denom, weighted gather-accumulate
        for (int c0 = r0; c0 < r1; c0 += 64) {
            int j = c0 + lane;
            float ev = 0.f;
            int p = 0;
            if (j < r1) {
                p = pe[j];
                int s = p & 0xffff, t = p >> 16;
                float av = __shfl(sqv, t) + sk[t * n_nodes + s];
                av = av >= 0.f ? av : NEG_SLOPE * av;
                ev = __expf(av - m);
            }
            float evs = ev;
            #pragma unroll
            for (int off = 32; off; off >>= 1) evs += __shfl_xor(evs, off);
            denom += evs;

            int C = r1 - c0;
            if (C > 64) C = 64;
            for (int jj = 0; jj < C; ++jj) {
                float evj = __shfl(ev, jj);
                int pj = __shfl(p, jj);
                int s = pj & 0xffff, t = pj >> 16;
                unsigned idx = ((unsigned)(t * n_nodes + s)) * CH + lane * 2;
                unsigned v = *(const unsigned*)(XW + idx);
                acc0 += evj * __uint_as_float(v << 16);
                acc1 += evj * __uint_as_float(v & 0xffff0000u);
            }
        }
    }

    float inv = denom > 0.f ? 1.f / denom : 0.f;  // deg==0 -> out = relu(bias)
    float2 b = *(const float2*)(bias + lane * 2);
    float o0 = acc0 * inv + b.x;
    float o1 = acc1 * inv + b.y;
    float2 o;
    o.x = o0 > 0.f ? o0 : 0.f;
    o.y = o1 > 0.f ? o1 : 0.f;
    *(float2*)(out + (size_t)wid * CH + lane * 2) = o;
}

// ---------- column sum over nodes ----------
__global__ __launch_bounds__(256) void k_colsum(const float* __restrict__ h,
                                                float* __restrict__ sum, int n_nodes) {
    int c = threadIdx.x & 127;
    int half = threadIdx.x >> 7;
    float acc = 0.f;
    for (int row = blockIdx.x * 2 + half; row < n_nodes; row += gridDim.x * 2)
        acc += h[(size_t)row * CH + c];
    atomicAdd(sum + c, acc);
}

// ---------- head: mean -> 128x16 matvec -> log_softmax ----------
__global__ void k_head(const float* __restrict__ sum, const float* __restrict__ lw,
                       const float* __restrict__ lb, float* __restrict__ outp, int n_nodes) {
    __shared__ float mean[CH];
    int t = threadIdx.x;  // 128
    mean[t] = sum[t] / (float)n_nodes;
    __syncthreads();
    if (t < OUT_CH) {
        float g = lb[t];
        for (int i = 0; i < CH; ++i) g += mean[i] * lw[i * OUT_CH + t];
        float m = g;
        #pragma unroll
        for (int off = 8; off; off >>= 1) m = fmaxf(m, __shfl_xor(m, off, 16));
        float ex = expf(g - m);
        float se = ex;
        #pragma unroll
        for (int off = 8; off; off >>= 1) se += __shfl_xor(se, off, 16);
        outp[t] = g - m - logf(se);
    }
}

extern "C" void kernel_launch(void* const* d_in, const int* in_sizes, int n_in,
                              void* d_out, int out_size, void* d_ws, size_t ws_size,
                              hipStream_t stream) {
    const float* x  = (const float*)d_in[0];
    const float* W1 = (const float*)d_in[1];
    const float* q1 = (const float*)d_in[2];
    const float* k1 = (const float*)d_in[3];
    const float* b1 = (const float*)d_in[4];
    const float* W2 = (const float*)d_in[5];
    const float* q2 = (const float*)d_in[6];
    const float* k2 = (const float*)d_in[7];
    const float* b2 = (const float*)d_in[8];
    const float* lw = (const float*)d_in[9];
    const float* lb = (const float*)d_in[10];
    const int* ei   = (const int*)d_in[11];
    const int* etp  = (const int*)d_in[12];

    const int n  = in_sizes[0] / CH;
    const int ne = in_sizes[12];
    const int* esrc = ei;
    const int* edst = ei + ne;

    char* ws = (char*)d_ws;
    size_t off = 0;
    auto carve = [&](size_t bytes) -> char* {
        char* p = ws + off;
        off = (off + bytes + 255) & ~(size_t)255;
        return p;
    };
    unsigned short* xw = (unsigned short*)carve((size_t)N_REL * n * CH * 2);
    float* h1     = (float*)carve((size_t)n * CH * 4);
    float* h2     = (float*)carve((size_t)n * CH * 4);
    float* sq     = (float*)carve((size_t)N_REL * n * 4);
    float* sk     = (float*)carve((size_t)N_REL * n * 4);
    float* wq     = (float*)carve(N_REL * CH * 4);
    float* wk     = (float*)carve(N_REL * CH * 4);
    int* count    = (int*)carve((size_t)n * 4);
    int* rowptr   = (int*)carve((size_t)(n + 1) * 4);
    int* rowptr_w = (int*)carve((size_t)n * 4);
    int* pe       = (int*)carve((size_t)ne * 4);
    float* sum128 = (float*)carve(CH * 4);

    hipMemsetAsync(count, 0, (size_t)n * 4, stream);
    hipMemsetAsync(sum128, 0, CH * 4, stream);

    // ---- CSR build (shared by both layers) ----
    k_hist<<<(ne + 255) / 256, 256, 0, stream>>>(edst, count, ne);
    k_scan<<<1, 1024, 0, stream>>>(count, rowptr, rowptr_w, n);
    k_scatter<<<(ne + 255) / 256, 256, 0, stream>>>(esrc, edst, etp, rowptr_w, pe, ne);

    auto run_layer = [&](const float* X, const float* W, const float* qv,
                         const float* kv, const float* bv, float* hout) {
        k_wqk<<<N_REL, CH, 0, stream>>>(W, qv, kv, wq, wk);
        k_gemm<<<dim3((n + 63) / 64, N_REL), 256, 0, stream>>>(X, W, xw, n);
        k_sqsk<<<(n + 3) / 4, 256, 0, stream>>>(X, wq, wk, sq, sk, n);
        k_node_attn<<<(n + 3) / 4, 256, 0, stream>>>(rowptr, pe, sq, sk, xw, bv, hout, n);
    };

    run_layer(x, W1, q1, k1, b1, h1);
    run_layer(h1, W2, q2, k2, b2, h2);

    k_colsum<<<256, 256, 0, stream>>>(h2, sum128, n);
    k_head<<<1, CH, 0, stream>>>(sum128, lw, lb, (float*)d_out, n);
}

// Round 3
// 532.159 us; speedup vs baseline: 3.8297x; 2.0718x over previous
//
#include <hip/hip_runtime.h>

#define CH 128
#define N_REL 8
#define OUT_CH 16
#define NEG_SLOPE 0.2f

typedef short short8 __attribute__((ext_vector_type(8)));
typedef float f32x4 __attribute__((ext_vector_type(4)));

// ---------- helpers ----------
__device__ __forceinline__ unsigned short f2bf(float f) {  // RTN-even f32->bf16
    unsigned u = __float_as_uint(f);
    return (unsigned short)((u + 0x7fffu + ((u >> 16) & 1u)) >> 16);
}

// ---------- wq[r] = W[r] @ q, wk[r] = W[r] @ k  (tiny) ----------
__global__ void k_wqk(const float* __restrict__ W, const float* __restrict__ qv,
                      const float* __restrict__ kv, float* __restrict__ wq,
                      float* __restrict__ wk) {
    int r = blockIdx.x;       // N_REL
    int i = threadIdx.x;      // CH
    const float* row = W + ((size_t)r * CH + i) * CH;
    float aq = 0.f, ak = 0.f;
    for (int o = 0; o < CH; ++o) { float w = row[o]; aq += w * qv[o]; ak += w * kv[o]; }
    wq[r * CH + i] = aq;
    wk[r * CH + i] = ak;
}

// ---------- X (fp32) -> Xb (bf16), 8 elems/thread ----------
__global__ void k_cast(const float* __restrict__ X, unsigned short* __restrict__ Xb,
                       long total) {
    long i = ((long)blockIdx.x * 256 + threadIdx.x) * 8;
    if (i >= total) return;
    float4 v0 = *(const float4*)(X + i);
    float4 v1 = *(const float4*)(X + i + 4);
    ushort4 a, b;
    a.x = f2bf(v0.x); a.y = f2bf(v0.y); a.z = f2bf(v0.z); a.w = f2bf(v0.w);
    b.x = f2bf(v1.x); b.y = f2bf(v1.y); b.z = f2bf(v1.z); b.w = f2bf(v1.w);
    *(ushort4*)(Xb + i) = a;
    *(ushort4*)(Xb + i + 4) = b;
}

// ---------- pack W[r] into A-fragment order (bf16) ----------
// Wpk[((r*8+ct)*4+ks)*64 + lane][i] = W[r][ks*32+(lane>>4)*8+i][ct*16+(lane&15)]
__global__ void k_wpack(const float* __restrict__ W, unsigned short* __restrict__ Wpk) {
    int t = blockIdx.x * 256 + threadIdx.x;
    if (t >= N_REL * 8 * 4 * 64) return;
    int lane = t & 63, ks = (t >> 6) & 3, ct = (t >> 8) & 7, r = t >> 11;
    int l15 = lane & 15, g = lane >> 4;
    const float* src = W + ((size_t)r * CH + ks * 32 + g * 8) * CH + ct * 16 + l15;
    unsigned pk[4];
    for (int p = 0; p < 4; ++p) {
        unsigned lo = f2bf(src[(2 * p) * CH]);
        unsigned hi = f2bf(src[(2 * p + 1) * CH]);
        pk[p] = lo | (hi << 16);
    }
    uint4 o = make_uint4(pk[0], pk[1], pk[2], pk[3]);
    *(uint4*)(Wpk + (size_t)t * 8) = o;
}

// ---------- XW[r] = X @ W[r] via bf16 MFMA (node-major bf16 output) ----------
// block = 4 waves, each wave: 16 nodes x 128 ch x 8 rel. X frags live in regs.
__global__ __launch_bounds__(256) void k_gemm2(const unsigned short* __restrict__ Xb,
                                               const unsigned short* __restrict__ Wpk,
                                               unsigned short* __restrict__ XW,
                                               int n) {
    const int tid = threadIdx.x;
    const int wv = tid >> 6, lane = tid & 63;
    const int l15 = lane & 15, g = lane >> 4;
    const int row = blockIdx.x * 64 + wv * 16 + l15;
    const int rowc = row < n ? row : n - 1;
    const bool ok = row < n;

    short8 xf[4];
    const unsigned short* xrow = Xb + (size_t)rowc * CH + g * 8;
    #pragma unroll
    for (int ks = 0; ks < 4; ++ks)
        xf[ks] = *(const short8*)(xrow + ks * 32);

    #pragma unroll 1
    for (int r = 0; r < N_REL; ++r) {
        unsigned short* orow = XW + ((size_t)r * n + row) * CH;
        const unsigned short* wr = Wpk + (size_t)r * 8 * 4 * 64 * 8 + (size_t)lane * 8;
        #pragma unroll
        for (int ct = 0; ct < 8; ++ct) {
            f32x4 a = {0.f, 0.f, 0.f, 0.f};
            const unsigned short* wp = wr + (size_t)ct * 4 * 64 * 8;
            #pragma unroll
            for (int ks = 0; ks < 4; ++ks) {
                short8 wf = *(const short8*)(wp + (size_t)ks * 64 * 8);
                a = __builtin_amdgcn_mfma_f32_16x16x32_bf16(wf, xf[ks], a, 0, 0, 0);
            }
            unsigned p01, p23;
            asm("v_cvt_pk_bf16_f32 %0, %1, %2" : "=v"(p01) : "v"(a[0]), "v"(a[1]));
            asm("v_cvt_pk_bf16_f32 %0, %1, %2" : "=v"(p23) : "v"(a[2]), "v"(a[3]));
            if (ok) *(uint2*)(orow + ct * 16 + g * 4) = make_uint2(p01, p23);
        }
    }
}

// ---------- sq[r][n] = x[n].wq[r], sk likewise (wave per node) ----------
__global__ __launch_bounds__(256) void k_sqsk(const float* __restrict__ X,
                                              const float* __restrict__ wq,
                                              const float* __restrict__ wk,
                                              float* __restrict__ sq,
                                              float* __restrict__ sk, int n_nodes) {
    int wave = (blockIdx.x * 256 + threadIdx.x) >> 6;
    int lane = threadIdx.x & 63;
    if (wave >= n_nodes) return;
    float x0 = X[(size_t)wave * CH + lane];
    float x1 = X[(size_t)wave * CH + 64 + lane];
    #pragma unroll
    for (int r = 0; r < N_REL; ++r) {
        float s1 = x0 * wq[r * CH + lane] + x1 * wq[r * CH + 64 + lane];
        float s2 = x0 * wk[r * CH + lane] + x1 * wk[r * CH + 64 + lane];
        #pragma unroll
        for (int off = 32; off; off >>= 1) {
            s1 += __shfl_xor(s1, off);
            s2 += __shfl_xor(s2, off);
        }
        if (lane == 0) { sq[r * n_nodes + wave] = s1; sk[r * n_nodes + wave] = s2; }
    }
}

// ---------- CSR build: histogram ----------
__global__ void k_hist(const int* __restrict__ dst, int* __restrict__ count, int ne) {
    int e = blockIdx.x * 256 + threadIdx.x;
    if (e >= ne) return;
    atomicAdd(count + dst[e], 1);
}

// ---------- CSR build: single-block exclusive scan (1024 threads) ----------
__global__ __launch_bounds__(1024) void k_scan(const int* __restrict__ count,
                                               int* __restrict__ rowptr,
                                               int* __restrict__ rowptr_work,
                                               int n_nodes) {
    __shared__ int wsum[16];
    __shared__ int wscan[16];
    __shared__ int carry_s;
    int tid = threadIdx.x, lane = tid & 63, w = tid >> 6;
    if (tid == 0) carry_s = 0;
    __syncthreads();
    for (int base = 0; base < n_nodes; base += 1024) {
        int i = base + tid;
        int v = (i < n_nodes) ? count[i] : 0;
        int s = v;
        #pragma unroll
        for (int off = 1; off < 64; off <<= 1) {
            int t = __shfl_up(s, off);
            if (lane >= off) s += t;
        }
        if (lane == 63) wsum[w] = s;
        __syncthreads();
        if (tid < 16) {
            int t = wsum[tid];
            #pragma unroll
            for (int off = 1; off < 16; off <<= 1) {
                int u = __shfl_up(t, off, 16);
                if ((lane & 15) >= off) t += u;
            }
            wscan[tid] = t;
        }
        __syncthreads();
        int wpref = (w == 0) ? 0 : wscan[w - 1];
        int excl = carry_s + wpref + s - v;
        if (i < n_nodes) { rowptr[i] = excl; rowptr_work[i] = excl; }
        __syncthreads();
        if (tid == 0) carry_s += wscan[15];
        __syncthreads();
    }
    if (tid == 0) rowptr[n_nodes] = carry_s;
}

// ---------- CSR build: scatter (src | et<<16 packed; src < 65536) ----------
__global__ void k_scatter(const int* __restrict__ src, const int* __restrict__ dst,
                          const int* __restrict__ et, int* __restrict__ rowptr_work,
                          int* __restrict__ pe, int ne) {
    int e = blockIdx.x * 256 + threadIdx.x;
    if (e >= ne) return;
    int pos = atomicAdd(rowptr_work + dst[e], 1);
    pe[pos] = (src[e] & 0xffff) | (et[e] << 16);
}

// ---------- fused per-node attention -> fp32 + bf16 outputs ----------
__global__ __launch_bounds__(256) void k_node_attn(
    const int* __restrict__ rowptr, const int* __restrict__ pe,
    const float* __restrict__ sq, const float* __restrict__ sk,
    const unsigned short* __restrict__ XW, const float* __restrict__ bias,
    float* __restrict__ out, unsigned short* __restrict__ outb, int n_nodes) {
    int wid = (blockIdx.x * 256 + threadIdx.x) >> 6;
    int lane = threadIdx.x & 63;
    if (wid >= n_nodes) return;
    int r0 = rowptr[wid], r1 = rowptr[wid + 1];
    float acc0 = 0.f, acc1 = 0.f, denom = 0.f;

    if (r1 > r0) {
        float sqv = (lane < N_REL) ? sq[lane * n_nodes + wid] : 0.f;

        float m = -1e30f;
        for (int c0 = r0; c0 < r1; c0 += 64) {
            int j = c0 + lane;
            float a = -1e30f;
            if (j < r1) {
                int p = pe[j];
                int s = p & 0xffff, t = p >> 16;
                float av = __shfl(sqv, t) + sk[t * n_nodes + s];
                a = av >= 0.f ? av : NEG_SLOPE * av;
            }
            m = fmaxf(m, a);
        }
        #pragma unroll
        for (int off = 32; off; off >>= 1) m = fmaxf(m, __shfl_xor(m, off));

        for (int c0 = r0; c0 < r1; c0 += 64) {
            int j = c0 + lane;
            float ev = 0.f;
            int p = 0;
            if (j < r1) {
                p = pe[j];
                int s = p & 0xffff, t = p >> 16;
                float av = __shfl(sqv, t) + sk[t * n_nodes + s];
                av = av >= 0.f ? av : NEG_SLOPE * av;
                ev = __expf(av - m);
            }
            float evs = ev;
            #pragma unroll
            for (int off = 32; off; off >>= 1) evs += __shfl_xor(evs, off);
            denom += evs;

            int C = r1 - c0;
            if (C > 64) C = 64;
            for (int jj = 0; jj < C; ++jj) {
                float evj = __shfl(ev, jj);
                int pj = __shfl(p, jj);
                int s = pj & 0xffff, t = pj >> 16;
                unsigned idx = ((unsigned)(t * n_nodes + s)) * CH + lane * 2;
                unsigned v = *(const unsigned*)(XW + idx);
                acc0 += evj * __uint_as_float(v << 16);
                acc1 += evj * __uint_as_float(v & 0xffff0000u);
            }
        }
    }

    float inv = denom > 0.f ? 1.f / denom : 0.f;
    float2 b = *(const float2*)(bias + lane * 2);
    float o0 = acc0 * inv + b.x;
    float o1 = acc1 * inv + b.y;
    o0 = o0 > 0.f ? o0 : 0.f;
    o1 = o1 > 0.f ? o1 : 0.f;
    *(float2*)(out + (size_t)wid * CH + lane * 2) = make_float2(o0, o1);
    unsigned pk = (unsigned)f2bf(o0) | ((unsigned)f2bf(o1) << 16);
    *(unsigned*)(outb + (size_t)wid * CH + lane * 2) = pk;
}

// ---------- column sum over nodes ----------
__global__ __launch_bounds__(256) void k_colsum(const float* __restrict__ h,
                                                float* __restrict__ sum, int n_nodes) {
    int c = threadIdx.x & 127;
    int half = threadIdx.x >> 7;
    float acc = 0.f;
    for (int row = blockIdx.x * 2 + half; row < n_nodes; row += gridDim.x * 2)
        acc += h[(size_t)row * CH + c];
    atomicAdd(sum + c, acc);
}

// ---------- head: mean -> 128x16 matvec -> log_softmax ----------
__global__ void k_head(const float* __restrict__ sum, const float* __restrict__ lw,
                       const float* __restrict__ lb, float* __restrict__ outp, int n_nodes) {
    __shared__ float mean[CH];
    int t = threadIdx.x;  // 128
    mean[t] = sum[t] / (float)n_nodes;
    __syncthreads();
    if (t < OUT_CH) {
        float g = lb[t];
        for (int i = 0; i < CH; ++i) g += mean[i] * lw[i * OUT_CH + t];
        float m = g;
        #pragma unroll
        for (int off = 8; off; off >>= 1) m = fmaxf(m, __shfl_xor(m, off, 16));
        float ex = expf(g - m);
        float se = ex;
        #pragma unroll
        for (int off = 8; off; off >>= 1) se += __shfl_xor(se, off, 16);
        outp[t] = g - m - logf(se);
    }
}

extern "C" void kernel_launch(void* const* d_in, const int* in_sizes, int n_in,
                              void* d_out, int out_size, void* d_ws, size_t ws_size,
                              hipStream_t stream) {
    const float* x  = (const float*)d_in[0];
    const float* W1 = (const float*)d_in[1];
    const float* q1 = (const float*)d_in[2];
    const float* k1 = (const float*)d_in[3];
    const float* b1 = (const float*)d_in[4];
    const float* W2 = (const float*)d_in[5];
    const float* q2 = (const float*)d_in[6];
    const float* k2 = (const float*)d_in[7];
    const float* b2 = (const float*)d_in[8];
    const float* lw = (const float*)d_in[9];
    const float* lb = (const float*)d_in[10];
    const int* ei   = (const int*)d_in[11];
    const int* etp  = (const int*)d_in[12];

    const int n  = in_sizes[0] / CH;
    const int ne = in_sizes[12];
    const int* esrc = ei;
    const int* edst = ei + ne;

    char* ws = (char*)d_ws;
    size_t off = 0;
    auto carve = [&](size_t bytes) -> char* {
        char* p = ws + off;
        off = (off + bytes + 255) & ~(size_t)255;
        return p;
    };
    unsigned short* xw  = (unsigned short*)carve((size_t)N_REL * n * CH * 2);
    float* h1     = (float*)carve((size_t)n * CH * 4);
    float* h2     = (float*)carve((size_t)n * CH * 4);
    unsigned short* xb  = (unsigned short*)carve((size_t)n * CH * 2);
    unsigned short* h1b = (unsigned short*)carve((size_t)n * CH * 2);
    unsigned short* h2b = (unsigned short*)carve((size_t)n * CH * 2);
    unsigned short* wpk = (unsigned short*)carve((size_t)N_REL * 8 * 4 * 64 * 8 * 2);
    float* sq     = (float*)carve((size_t)N_REL * n * 4);
    float* sk     = (float*)carve((size_t)N_REL * n * 4);
    float* wq     = (float*)carve(N_REL * CH * 4);
    float* wk     = (float*)carve(N_REL * CH * 4);
    int* count    = (int*)carve((size_t)n * 4);
    int* rowptr   = (int*)carve((size_t)(n + 1) * 4);
    int* rowptr_w = (int*)carve((size_t)n * 4);
    int* pe       = (int*)carve((size_t)ne * 4);
    float* sum128 = (float*)carve(CH * 4);

    hipMemsetAsync(count, 0, (size_t)n * 4, stream);
    hipMemsetAsync(sum128, 0, CH * 4, stream);

    // ---- CSR build (shared by both layers) ----
    k_hist<<<(ne + 255) / 256, 256, 0, stream>>>(edst, count, ne);
    k_scan<<<1, 1024, 0, stream>>>(count, rowptr, rowptr_w, n);
    k_scatter<<<(ne + 255) / 256, 256, 0, stream>>>(esrc, edst, etp, rowptr_w, pe, ne);

    const int wpack_threads = N_REL * 8 * 4 * 64;

    auto run_layer = [&](const float* X, const unsigned short* Xb, const float* W,
                         const float* qv, const float* kv, const float* bv,
                         float* hout, unsigned short* houtb) {
        k_wqk<<<N_REL, CH, 0, stream>>>(W, qv, kv, wq, wk);
        k_wpack<<<(wpack_threads + 255) / 256, 256, 0, stream>>>(W, wpk);
        k_gemm2<<<(n + 63) / 64, 256, 0, stream>>>(Xb, wpk, xw, n);
        k_sqsk<<<(n + 3) / 4, 256, 0, stream>>>(X, wq, wk, sq, sk, n);
        k_node_attn<<<(n + 3) / 4, 256, 0, stream>>>(rowptr, pe, sq, sk, xw, bv, hout, houtb, n);
    };

    k_cast<<<(int)(((long)n * CH / 8 + 255) / 256), 256, 0, stream>>>(x, xb, (long)n * CH);
    run_layer(x, xb, W1, q1, k1, b1, h1, h1b);
    run_layer(h1, h1b, W2, q2, k2, b2, h2, h2b);

    k_colsum<<<256, 256, 0, stream>>>(h2, sum128, n);
    k_head<<<1, CH, 0, stream>>>(sum128, lw, lb, (float*)d_out, n);
}

// Round 5
// 471.965 us; speedup vs baseline: 4.3181x; 1.1275x over previous
//
#include <hip/hip_runtime.h>

#define CH 128
#define N_REL 8
#define OUT_CH 16
#define NEG_SLOPE 0.2f

typedef short short8 __attribute__((ext_vector_type(8)));
typedef float f32x4 __attribute__((ext_vector_type(4)));

// ---------- helpers ----------
__device__ __forceinline__ unsigned short f2bf(float f) {  // RTN-even f32->bf16
    unsigned u = __float_as_uint(f);
    return (unsigned short)((u + 0x7fffu + ((u >> 16) & 1u)) >> 16);
}

// ---------- wq[r] = W[r] @ q, wk[r] = W[r] @ k  (tiny) ----------
__global__ void k_wqk(const float* __restrict__ W, const float* __restrict__ qv,
                      const float* __restrict__ kv, float* __restrict__ wq,
                      float* __restrict__ wk) {
    int r = blockIdx.x;       // N_REL
    int i = threadIdx.x;      // CH
    const float* row = W + ((size_t)r * CH + i) * CH;
    float aq = 0.f, ak = 0.f;
    for (int o = 0; o < CH; ++o) { float w = row[o]; aq += w * qv[o]; ak += w * kv[o]; }
    wq[r * CH + i] = aq;
    wk[r * CH + i] = ak;
}

// ---------- X (fp32) -> Xb (bf16), 8 elems/thread ----------
__global__ void k_cast(const float* __restrict__ X, unsigned short* __restrict__ Xb,
                       long total) {
    long i = ((long)blockIdx.x * 256 + threadIdx.x) * 8;
    if (i >= total) return;
    float4 v0 = *(const float4*)(X + i);
    float4 v1 = *(const float4*)(X + i + 4);
    ushort4 a, b;
    a.x = f2bf(v0.x); a.y = f2bf(v0.y); a.z = f2bf(v0.z); a.w = f2bf(v0.w);
    b.x = f2bf(v1.x); b.y = f2bf(v1.y); b.z = f2bf(v1.z); b.w = f2bf(v1.w);
    *(ushort4*)(Xb + i) = a;
    *(ushort4*)(Xb + i + 4) = b;
}

// ---------- pack W[r] into A-fragment order (bf16) ----------
// Wpk[((r*8+ct)*4+ks)*64 + lane][i] = W[r][ks*32+(lane>>4)*8+i][ct*16+(lane&15)]
__global__ void k_wpack(const float* __restrict__ W, unsigned short* __restrict__ Wpk) {
    int t = blockIdx.x * 256 + threadIdx.x;
    if (t >= N_REL * 8 * 4 * 64) return;
    int lane = t & 63, ks = (t >> 6) & 3, ct = (t >> 8) & 7, r = t >> 11;
    int l15 = lane & 15, g = lane >> 4;
    const float* src = W + ((size_t)r * CH + ks * 32 + g * 8) * CH + ct * 16 + l15;
    unsigned pk[4];
    for (int p = 0; p < 4; ++p) {
        unsigned lo = f2bf(src[(2 * p) * CH]);
        unsigned hi = f2bf(src[(2 * p + 1) * CH]);
        pk[p] = lo | (hi << 16);
    }
    uint4 o = make_uint4(pk[0], pk[1], pk[2], pk[3]);
    *(uint4*)(Wpk + (size_t)t * 8) = o;
}

// ---------- XW[r] = X @ W[r] via bf16 MFMA, relation-resident W in VGPRs ----------
// wave w: relation r = w&7, tile-slot = w>>3; grid-strides over 16-node tiles.
__global__ __launch_bounds__(256) void k_gemm3(const unsigned short* __restrict__ Xb,
                                               const unsigned short* __restrict__ Wpk,
                                               unsigned short* __restrict__ XW,
                                               int n, int nwaves) {
    const int wv = threadIdx.x >> 6, lane = threadIdx.x & 63;
    const int l15 = lane & 15, g = lane >> 4;
    const int w = blockIdx.x * 4 + wv;
    const int r = w & 7;
    const int slot = w >> 3;
    const int nslots = nwaves >> 3;
    const int ntiles = (n + 15) >> 4;

    // W fragments resident for the wave's lifetime (32 x 16B = 128 VGPR)
    short8 wf[8][4];
    const unsigned short* wr = Wpk + ((size_t)r * 32 * 64 + lane) * 8;
    #pragma unroll
    for (int ct = 0; ct < 8; ++ct)
        #pragma unroll
        for (int ks = 0; ks < 4; ++ks)
            wf[ct][ks] = *(const short8*)(wr + (size_t)(ct * 4 + ks) * 64 * 8);

    for (int t = slot; t < ntiles; t += nslots) {
        int row = t * 16 + l15;
        bool ok = row < n;
        int rowc = ok ? row : n - 1;
        const unsigned short* xrow = Xb + (size_t)rowc * CH + g * 8;
        short8 xf[4];
        #pragma unroll
        for (int ks = 0; ks < 4; ++ks) xf[ks] = *(const short8*)(xrow + ks * 32);
        unsigned short* orow = XW + ((size_t)r * n + row) * CH;
        #pragma unroll
        for (int ct = 0; ct < 8; ++ct) {
            f32x4 a = {0.f, 0.f, 0.f, 0.f};
            #pragma unroll
            for (int ks = 0; ks < 4; ++ks)
                a = __builtin_amdgcn_mfma_f32_16x16x32_bf16(wf[ct][ks], xf[ks], a, 0, 0, 0);
            unsigned p01, p23;
            asm("v_cvt_pk_bf16_f32 %0, %1, %2" : "=v"(p01) : "v"(a[0]), "v"(a[1]));
            asm("v_cvt_pk_bf16_f32 %0, %1, %2" : "=v"(p23) : "v"(a[2]), "v"(a[3]));
            if (ok) *(uint2*)(orow + ct * 16 + g * 4) = make_uint2(p01, p23);
        }
    }
}

// ---------- sq[r][n] = x[n].wq[r], sk likewise (wave per node) ----------
__global__ __launch_bounds__(256) void k_sqsk(const float* __restrict__ X,
                                              const float* __restrict__ wq,
                                              const float* __restrict__ wk,
                                              float* __restrict__ sq,
                                              float* __restrict__ sk, int n_nodes) {
    int wave = (blockIdx.x * 256 + threadIdx.x) >> 6;
    int lane = threadIdx.x & 63;
    if (wave >= n_nodes) return;
    float x0 = X[(size_t)wave * CH + lane];
    float x1 = X[(size_t)wave * CH + 64 + lane];
    #pragma unroll
    for (int r = 0; r < N_REL; ++r) {
        float s1 = x0 * wq[r * CH + lane] + x1 * wq[r * CH + 64 + lane];
        float s2 = x0 * wk[r * CH + lane] + x1 * wk[r * CH + 64 + lane];
        #pragma unroll
        for (int off = 32; off; off >>= 1) {
            s1 += __shfl_xor(s1, off);
            s2 += __shfl_xor(s2, off);
        }
        if (lane == 0) { sq[r * n_nodes + wave] = s1; sk[r * n_nodes + wave] = s2; }
    }
}

// ---------- CSR build: histogram ----------
__global__ void k_hist(const int* __restrict__ dst, int* __restrict__ count, int ne) {
    int e = blockIdx.x * 256 + threadIdx.x;
    if (e >= ne) return;
    atomicAdd(count + dst[e], 1);
}

// ---------- CSR build: single-block exclusive scan (1024 threads) ----------
__global__ __launch_bounds__(1024) void k_scan(const int* __restrict__ count,
                                               int* __restrict__ rowptr,
                                               int* __restrict__ rowptr_work,
                                               int n_nodes) {
    __shared__ int wsum[16];
    __shared__ int wscan[16];
    __shared__ int carry_s;
    int tid = threadIdx.x, lane = tid & 63, w = tid >> 6;
    if (tid == 0) carry_s = 0;
    __syncthreads();
    for (int base = 0; base < n_nodes; base += 1024) {
        int i = base + tid;
        int v = (i < n_nodes) ? count[i] : 0;
        int s = v;
        #pragma unroll
        for (int off = 1; off < 64; off <<= 1) {
            int t = __shfl_up(s, off);
            if (lane >= off) s += t;
        }
        if (lane == 63) wsum[w] = s;
        __syncthreads();
        if (tid < 16) {
            int t = wsum[tid];
            #pragma unroll
            for (int off = 1; off < 16; off <<= 1) {
                int u = __shfl_up(t, off, 16);
                if ((lane & 15) >= off) t += u;
            }
            wscan[tid] = t;
        }
        __syncthreads();
        int wpref = (w == 0) ? 0 : wscan[w - 1];
        int excl = carry_s + wpref + s - v;
        if (i < n_nodes) { rowptr[i] = excl; rowptr_work[i] = excl; }
        __syncthreads();
        if (tid == 0) carry_s += wscan[15];
        __syncthreads();
    }
    if (tid == 0) rowptr[n_nodes] = carry_s;
}

// ---------- CSR build: scatter (src | et<<16 packed; src < 65536) ----------
__global__ void k_scatter(const int* __restrict__ src, const int* __restrict__ dst,
                          const int* __restrict__ et, int* __restrict__ rowptr_work,
                          int* __restrict__ pe, int ne) {
    int e = blockIdx.x * 256 + threadIdx.x;
    if (e >= ne) return;
    int pos = atomicAdd(rowptr_work + dst[e], 1);
    pe[pos] = (src[e] & 0xffff) | (et[e] << 16);
}

// ---------- fused per-node attention -> fp32 + bf16 outputs ----------
__global__ __launch_bounds__(256) void k_node_attn(
    const int* __restrict__ rowptr, const int* __restrict__ pe,
    const float* __restrict__ sq, const float* __restrict__ sk,
    const unsigned short* __restrict__ XW, const float* __restrict__ bias,
    float* __restrict__ out, unsigned short* __restrict__ outb, int n_nodes) {
    int wid = (blockIdx.x * 256 + threadIdx.x) >> 6;
    int lane = threadIdx.x & 63;
    if (wid >= n_nodes) return;
    int r0 = rowptr[wid], r1 = rowptr[wid + 1];
    float acc0 = 0.f, acc1 = 0.f, denom = 0.f;

    if (r1 > r0) {
        float sqv = (lane < N_REL) ? sq[lane * n_nodes + wid] : 0.f;

        float m = -1e30f;
        for (int c0 = r0; c0 < r1; c0 += 64) {
            int j = c0 + lane;
            float a = -1e30f;
            if (j < r1) {
                int p = pe[j];
                int s = p & 0xffff, t = p >> 16;
                float av = __shfl(sqv, t) + sk[t * n_nodes + s];
                a = av >= 0.f ? av : NEG_SLOPE * av;
            }
            m = fmaxf(m, a);
        }
        #pragma unroll
        for (int off = 32; off; off >>= 1) m = fmaxf(m, __shfl_xor(m, off));

        for (int c0 = r0; c0 < r1; c0 += 64) {
            int j = c0 + lane;
            float ev = 0.f;
            int p = 0;
            if (j < r1) {
                p = pe[j];
                int s = p & 0xffff, t = p >> 16;
                float av = __shfl(sqv, t) + sk[t * n_nodes + s];
                av = av >= 0.f ? av : NEG_SLOPE * av;
                ev = __expf(av - m);
            }
            float evs = ev;
            #pragma unroll
            for (int off = 32; off; off >>= 1) evs += __shfl_xor(evs, off);
            denom += evs;

            int C = r1 - c0;
            if (C > 64) C = 64;
            for (int jj = 0; jj < C; ++jj) {
                float evj = __shfl(ev, jj);
                int pj = __shfl(p, jj);
                int s = pj & 0xffff, t = pj >> 16;
                unsigned idx = ((unsigned)(t * n_nodes + s)) * CH + lane * 2;
                unsigned v = *(const unsigned*)(XW + idx);
                acc0 += evj * __uint_as_float(v << 16);
                acc1 += evj * __uint_as_float(v & 0xffff0000u);
            }
        }
    }

    float inv = denom > 0.f ? 1.f / denom : 0.f;
    float2 b = *(const float2*)(bias + lane * 2);
    float o0 = acc0 * inv + b.x;
    float o1 = acc1 * inv + b.y;
    o0 = o0 > 0.f ? o0 : 0.f;
    o1 = o1 > 0.f ? o1 : 0.f;
    *(float2*)(out + (size_t)wid * CH + lane * 2) = make_float2(o0, o1);
    unsigned pk = (unsigned)f2bf(o0) | ((unsigned)f2bf(o1) << 16);
    *(unsigned*)(outb + (size_t)wid * CH + lane * 2) = pk;
}

// ---------- column sum over nodes ----------
__global__ __launch_bounds__(256) void k_colsum(const float* __restrict__ h,
                                                float* __restrict__ sum, int n_nodes) {
    int c = threadIdx.x & 127;
    int half = threadIdx.x >> 7;
    float acc = 0.f;
    for (int row = blockIdx.x * 2 + half; row < n_nodes; row += gridDim.x * 2)
        acc += h[(size_t)row * CH + c];
    atomicAdd(sum + c, acc);
}

// ---------- head: mean -> 128x16 matvec -> log_softmax ----------
__global__ void k_head(const float* __restrict__ sum, const float* __restrict__ lw,
                       const float* __restrict__ lb, float* __restrict__ outp, int n_nodes) {
    __shared__ float mean[CH];
    int t = threadIdx.x;  // 128
    mean[t] = sum[t] / (float)n_nodes;
    __syncthreads();
    if (t < OUT_CH) {
        float g = lb[t];
        for (int i = 0; i < CH; ++i) g += mean[i] * lw[i * OUT_CH + t];
        float m = g;
        #pragma unroll
        for (int off = 8; off; off >>= 1) m = fmaxf(m, __shfl_xor(m, off, 16));
        float ex = expf(g - m);
        float se = ex;
        #pragma unroll
        for (int off = 8; off; off >>= 1) se += __shfl_xor(se, off, 16);
        outp[t] = g - m - logf(se);
    }
}

extern "C" void kernel_launch(void* const* d_in, const int* in_sizes, int n_in,
                              void* d_out, int out_size, void* d_ws, size_t ws_size,
                              hipStream_t stream) {
    const float* x  = (const float*)d_in[0];
    const float* W1 = (const float*)d_in[1];
    const float* q1 = (const float*)d_in[2];
    const float* k1 = (const float*)d_in[3];
    const float* b1 = (const float*)d_in[4];
    const float* W2 = (const float*)d_in[5];
    const float* q2 = (const float*)d_in[6];
    const float* k2 = (const float*)d_in[7];
    const float* b2 = (const float*)d_in[8];
    const float* lw = (const float*)d_in[9];
    const float* lb = (const float*)d_in[10];
    const int* ei   = (const int*)d_in[11];
    const int* etp  = (const int*)d_in[12];

    const int n  = in_sizes[0] / CH;
    const int ne = in_sizes[12];
    const int* esrc = ei;
    const int* edst = ei + ne;

    char* ws = (char*)d_ws;
    size_t off = 0;
    auto carve = [&](size_t bytes) -> char* {
        char* p = ws + off;
        off = (off + bytes + 255) & ~(size_t)255;
        return p;
    };
    unsigned short* xw  = (unsigned short*)carve((size_t)N_REL * n * CH * 2);
    float* h1     = (float*)carve((size_t)n * CH * 4);
    float* h2     = (float*)carve((size_t)n * CH * 4);
    unsigned short* xb  = (unsigned short*)carve((size_t)n * CH * 2);
    unsigned short* h1b = (unsigned short*)carve((size_t)n * CH * 2);
    unsigned short* h2b = (unsigned short*)carve((size_t)n * CH * 2);
    unsigned short* wpk = (unsigned short*)carve((size_t)N_REL * 32 * 64 * 8 * 2);
    float* sq     = (float*)carve((size_t)N_REL * n * 4);
    float* sk     = (float*)carve((size_t)N_REL * n * 4);
    float* wq     = (float*)carve(N_REL * CH * 4);
    float* wk     = (float*)carve(N_REL * CH * 4);
    int* count    = (int*)carve((size_t)n * 4);
    int* rowptr   = (int*)carve((size_t)(n + 1) * 4);
    int* rowptr_w = (int*)carve((size_t)n * 4);
    int* pe       = (int*)carve((size_t)ne * 4);
    float* sum128 = (float*)carve(CH * 4);

    hipMemsetAsync(count, 0, (size_t)n * 4, stream);
    hipMemsetAsync(sum128, 0, CH * 4, stream);

    // ---- CSR build (shared by both layers) ----
    k_hist<<<(ne + 255) / 256, 256, 0, stream>>>(edst, count, ne);
    k_scan<<<1, 1024, 0, stream>>>(count, rowptr, rowptr_w, n);
    k_scatter<<<(ne + 255) / 256, 256, 0, stream>>>(esrc, edst, etp, rowptr_w, pe, ne);

    const int wpack_threads = N_REL * 8 * 4 * 64;
    const int NW = 2048;  // 512 blocks x 4 waves

    auto run_layer = [&](const float* X, const unsigned short* Xb, const float* W,
                         const float* qv, const float* kv, const float* bv,
                         float* hout, unsigned short* houtb) {
        k_wqk<<<N_REL, CH, 0, stream>>>(W, qv, kv, wq, wk);
        k_wpack<<<(wpack_threads + 255) / 256, 256, 0, stream>>>(W, wpk);
        k_gemm3<<<NW / 4, 256, 0, stream>>>(Xb, wpk, xw, n, NW);
        k_sqsk<<<(n + 3) / 4, 256, 0, stream>>>(X, wq, wk, sq, sk, n);
        k_node_attn<<<(n + 3) / 4, 256, 0, stream>>>(rowptr, pe, sq, sk, xw, bv, hout, houtb, n);
    };

    k_cast<<<(int)(((long)n * CH / 8 + 255) / 256), 256, 0, stream>>>(x, xb, (long)n * CH);
    run_layer(x, xb, W1, q1, k1, b1, h1, h1b);
    run_layer(h1, h1b, W2, q2, k2, b2, h2, h2b);

    k_colsum<<<256, 256, 0, stream>>>(h2, sum128, n);
    k_head<<<1, CH, 0, stream>>>(sum128, lw, lb, (float*)d_out, n);
}

// Round 6
// 415.661 us; speedup vs baseline: 4.9031x; 1.1355x over previous
//
#include <hip/hip_runtime.h>

#define CH 128
#define N_REL 8
#define OUT_CH 16
#define NEG_SLOPE 0.2f

typedef short short8 __attribute__((ext_vector_type(8)));
typedef float f32x4 __attribute__((ext_vector_type(4)));

// ---------- helpers ----------
__device__ __forceinline__ unsigned short f2bf(float f) {  // RTN-even f32->bf16
    unsigned u = __float_as_uint(f);
    return (unsigned short)((u + 0x7fffu + ((u >> 16) & 1u)) >> 16);
}

// ---------- wq[r] = W[r] @ q, wk[r] = W[r] @ k  (tiny) ----------
__global__ void k_wqk(const float* __restrict__ W, const float* __restrict__ qv,
                      const float* __restrict__ kv, float* __restrict__ wq,
                      float* __restrict__ wk) {
    int r = blockIdx.x;       // N_REL
    int i = threadIdx.x;      // CH
    const float* row = W + ((size_t)r * CH + i) * CH;
    float aq = 0.f, ak = 0.f;
    for (int o = 0; o < CH; ++o) { float w = row[o]; aq += w * qv[o]; ak += w * kv[o]; }
    wq[r * CH + i] = aq;
    wk[r * CH + i] = ak;
}

// ---------- X (fp32) -> Xb (bf16), 8 elems/thread ----------
__global__ void k_cast(const float* __restrict__ X, unsigned short* __restrict__ Xb,
                       long total) {
    long i = ((long)blockIdx.x * 256 + threadIdx.x) * 8;
    if (i >= total) return;
    float4 v0 = *(const float4*)(X + i);
    float4 v1 = *(const float4*)(X + i + 4);
    ushort4 a, b;
    a.x = f2bf(v0.x); a.y = f2bf(v0.y); a.z = f2bf(v0.z); a.w = f2bf(v0.w);
    b.x = f2bf(v1.x); b.y = f2bf(v1.y); b.z = f2bf(v1.z); b.w = f2bf(v1.w);
    *(ushort4*)(Xb + i) = a;
    *(ushort4*)(Xb + i + 4) = b;
}

// ---------- pack W[r] into A-fragment order (bf16) ----------
// Wpk[((r*8+ct)*4+ks)*64 + lane][i] = W[r][ks*32+(lane>>4)*8+i][ct*16+(lane&15)]
__global__ void k_wpack(const float* __restrict__ W, unsigned short* __restrict__ Wpk) {
    int t = blockIdx.x * 256 + threadIdx.x;
    if (t >= N_REL * 8 * 4 * 64) return;
    int lane = t & 63, ks = (t >> 6) & 3, ct = (t >> 8) & 7, r = t >> 11;
    int l15 = lane & 15, g = lane >> 4;
    const float* src = W + ((size_t)r * CH + ks * 32 + g * 8) * CH + ct * 16 + l15;
    unsigned pk[4];
    for (int p = 0; p < 4; ++p) {
        unsigned lo = f2bf(src[(2 * p) * CH]);
        unsigned hi = f2bf(src[(2 * p + 1) * CH]);
        pk[p] = lo | (hi << 16);
    }
    uint4 o = make_uint4(pk[0], pk[1], pk[2], pk[3]);
    *(uint4*)(Wpk + (size_t)t * 8) = o;
}

// ---------- XW[r] = X @ W[r] via bf16 MFMA, relation-resident W in VGPRs ----------
__global__ __launch_bounds__(256) void k_gemm3(const unsigned short* __restrict__ Xb,
                                               const unsigned short* __restrict__ Wpk,
                                               unsigned short* __restrict__ XW,
                                               int n, int nwaves) {
    const int wv = threadIdx.x >> 6, lane = threadIdx.x & 63;
    const int l15 = lane & 15, g = lane >> 4;
    const int w = blockIdx.x * 4 + wv;
    const int r = w & 7;
    const int slot = w >> 3;
    const int nslots = nwaves >> 3;
    const int ntiles = (n + 15) >> 4;

    short8 wf[8][4];
    const unsigned short* wr = Wpk + ((size_t)r * 32 * 64 + lane) * 8;
    #pragma unroll
    for (int ct = 0; ct < 8; ++ct)
        #pragma unroll
        for (int ks = 0; ks < 4; ++ks)
            wf[ct][ks] = *(const short8*)(wr + (size_t)(ct * 4 + ks) * 64 * 8);

    for (int t = slot; t < ntiles; t += nslots) {
        int row = t * 16 + l15;
        bool ok = row < n;
        int rowc = ok ? row : n - 1;
        const unsigned short* xrow = Xb + (size_t)rowc * CH + g * 8;
        short8 xf[4];
        #pragma unroll
        for (int ks = 0; ks < 4; ++ks) xf[ks] = *(const short8*)(xrow + ks * 32);
        unsigned short* orow = XW + ((size_t)r * n + row) * CH;
        #pragma unroll
        for (int ct = 0; ct < 8; ++ct) {
            f32x4 a = {0.f, 0.f, 0.f, 0.f};
            #pragma unroll
            for (int ks = 0; ks < 4; ++ks)
                a = __builtin_amdgcn_mfma_f32_16x16x32_bf16(wf[ct][ks], xf[ks], a, 0, 0, 0);
            unsigned p01, p23;
            asm("v_cvt_pk_bf16_f32 %0, %1, %2" : "=v"(p01) : "v"(a[0]), "v"(a[1]));
            asm("v_cvt_pk_bf16_f32 %0, %1, %2" : "=v"(p23) : "v"(a[2]), "v"(a[3]));
            if (ok) *(uint2*)(orow + ct * 16 + g * 4) = make_uint2(p01, p23);
        }
    }
}

// ---------- sq/sk from bf16 activations (wave per node) ----------
__global__ __launch_bounds__(256) void k_sqsk(const unsigned short* __restrict__ Xb,
                                              const float* __restrict__ wq,
                                              const float* __restrict__ wk,
                                              float* __restrict__ sq,
                                              float* __restrict__ sk, int n_nodes) {
    int wave = (blockIdx.x * 256 + threadIdx.x) >> 6;
    int lane = threadIdx.x & 63;
    if (wave >= n_nodes) return;
    unsigned v = *(const unsigned*)(Xb + (size_t)wave * CH + lane * 2);
    float x0 = __uint_as_float(v << 16);
    float x1 = __uint_as_float(v & 0xffff0000u);
    #pragma unroll
    for (int r = 0; r < N_REL; ++r) {
        float2 q2 = *(const float2*)(wq + r * CH + lane * 2);
        float2 k2 = *(const float2*)(wk + r * CH + lane * 2);
        float s1 = x0 * q2.x + x1 * q2.y;
        float s2 = x0 * k2.x + x1 * k2.y;
        #pragma unroll
        for (int off = 32; off; off >>= 1) {
            s1 += __shfl_xor(s1, off);
            s2 += __shfl_xor(s2, off);
        }
        if (lane == 0) { sq[r * n_nodes + wave] = s1; sk[r * n_nodes + wave] = s2; }
    }
}

// ---------- CSR build: histogram ----------
__global__ void k_hist(const int* __restrict__ dst, int* __restrict__ count, int ne) {
    int e = blockIdx.x * 256 + threadIdx.x;
    if (e >= ne) return;
    atomicAdd(count + dst[e], 1);
}

// ---------- CSR build: single-block exclusive scan (1024 threads) ----------
__global__ __launch_bounds__(1024) void k_scan(const int* __restrict__ count,
                                               int* __restrict__ rowptr,
                                               int* __restrict__ rowptr_work,
                                               int n_nodes) {
    __shared__ int wsum[16];
    __shared__ int wscan[16];
    __shared__ int carry_s;
    int tid = threadIdx.x, lane = tid & 63, w = tid >> 6;
    if (tid == 0) carry_s = 0;
    __syncthreads();
    for (int base = 0; base < n_nodes; base += 1024) {
        int i = base + tid;
        int v = (i < n_nodes) ? count[i] : 0;
        int s = v;
        #pragma unroll
        for (int off = 1; off < 64; off <<= 1) {
            int t = __shfl_up(s, off);
            if (lane >= off) s += t;
        }
        if (lane == 63) wsum[w] = s;
        __syncthreads();
        if (tid < 16) {
            int t = wsum[tid];
            #pragma unroll
            for (int off = 1; off < 16; off <<= 1) {
                int u = __shfl_up(t, off, 16);
                if ((lane & 15) >= off) t += u;
            }
            wscan[tid] = t;
        }
        __syncthreads();
        int wpref = (w == 0) ? 0 : wscan[w - 1];
        int excl = carry_s + wpref + s - v;
        if (i < n_nodes) { rowptr[i] = excl; rowptr_work[i] = excl; }
        __syncthreads();
        if (tid == 0) carry_s += wscan[15];
        __syncthreads();
    }
    if (tid == 0) rowptr[n_nodes] = carry_s;
}

// ---------- CSR build: scatter (src | et<<16 packed; src < 65536) ----------
__global__ void k_scatter(const int* __restrict__ src, const int* __restrict__ dst,
                          const int* __restrict__ et, int* __restrict__ rowptr_work,
                          int* __restrict__ pe, int ne) {
    int e = blockIdx.x * 256 + threadIdx.x;
    if (e >= ne) return;
    int pos = atomicAdd(rowptr_work + dst[e], 1);
    pe[pos] = (src[e] & 0xffff) | (et[e] << 16);
}

// ---------- fused per-node attention -> bf16 output ----------
// wave per node; gather: 4 edges/iter (g=lane>>4), 16B (8 ch) per lane (l16=lane&15)
__global__ __launch_bounds__(256) void k_attn(
    const int* __restrict__ rowptr, const int* __restrict__ pe,
    const float* __restrict__ sq, const float* __restrict__ sk,
    const unsigned short* __restrict__ XW, const float* __restrict__ bias,
    unsigned short* __restrict__ outb, int n_nodes) {
    int wid = (blockIdx.x * 256 + threadIdx.x) >> 6;
    int lane = threadIdx.x & 63;
    if (wid >= n_nodes) return;
    const int l16 = lane & 15, g16 = lane >> 4;
    int r0 = rowptr[wid], r1 = rowptr[wid + 1];
    float acc[8] = {};
    float denom = 0.f;

    if (r1 > r0) {
        float sqv = (lane < N_REL) ? sq[lane * n_nodes + wid] : 0.f;

        // pass 1: global max
        float m = -1e30f;
        for (int c0 = r0; c0 < r1; c0 += 64) {
            int j = c0 + lane;
            float a = -1e30f;
            if (j < r1) {
                int p = pe[j];
                int s = p & 0xffff, t = p >> 16;
                float av = __shfl(sqv, t) + sk[t * n_nodes + s];
                a = av >= 0.f ? av : NEG_SLOPE * av;
            }
            m = fmaxf(m, a);
        }
        #pragma unroll
        for (int off = 32; off; off >>= 1) m = fmaxf(m, __shfl_xor(m, off));

        // pass 2: exp + denom + wide gather
        for (int c0 = r0; c0 < r1; c0 += 64) {
            int j = c0 + lane;
            float ev = 0.f;
            int p = 0;
            if (j < r1) {
                p = pe[j];
                int s = p & 0xffff, t = p >> 16;
                float av = __shfl(sqv, t) + sk[t * n_nodes + s];
                av = av >= 0.f ? av : NEG_SLOPE * av;
                ev = __expf(av - m);
            }
            float evs = ev;
            #pragma unroll
            for (int off = 32; off; off >>= 1) evs += __shfl_xor(evs, off);
            denom += evs;

            int C = r1 - c0;
            if (C > 64) C = 64;
            for (int jj = 0; jj < C; jj += 4) {
                int lsel = jj + g16;                  // lane holding edge jj+g16
                float evj = __shfl(ev, lsel);         // 0 for lanes past C
                int pj = __shfl(p, lsel);
                int s = pj & 0xffff, t = pj >> 16;
                const unsigned short* row = XW + ((size_t)(t * n_nodes + s)) * CH + l16 * 8;
                uint4 v = *(const uint4*)row;
                acc[0] += evj * __uint_as_float(v.x << 16);
                acc[1] += evj * __uint_as_float(v.x & 0xffff0000u);
                acc[2] += evj * __uint_as_float(v.y << 16);
                acc[3] += evj * __uint_as_float(v.y & 0xffff0000u);
                acc[4] += evj * __uint_as_float(v.z << 16);
                acc[5] += evj * __uint_as_float(v.z & 0xffff0000u);
                acc[6] += evj * __uint_as_float(v.w << 16);
                acc[7] += evj * __uint_as_float(v.w & 0xffff0000u);
            }
        }
    }

    // combine the 4 edge-groups
    #pragma unroll
    for (int i = 0; i < 8; ++i) {
        acc[i] += __shfl_xor(acc[i], 16);
        acc[i] += __shfl_xor(acc[i], 32);
    }

    if (lane < 16) {
        float inv = denom > 0.f ? 1.f / denom : 0.f;
        unsigned pk[4];
        #pragma unroll
        for (int i = 0; i < 4; ++i) {
            float b0 = bias[l16 * 8 + 2 * i];
            float b1 = bias[l16 * 8 + 2 * i + 1];
            float o0 = acc[2 * i] * inv + b0;
            float o1 = acc[2 * i + 1] * inv + b1;
            o0 = o0 > 0.f ? o0 : 0.f;
            o1 = o1 > 0.f ? o1 : 0.f;
            pk[i] = (unsigned)f2bf(o0) | ((unsigned)f2bf(o1) << 16);
        }
        *(uint4*)(outb + (size_t)wid * CH + l16 * 8) = make_uint4(pk[0], pk[1], pk[2], pk[3]);
    }
}

// ---------- column sum over nodes (bf16 input, LDS block reduce) ----------
__global__ __launch_bounds__(256) void k_colsum(const unsigned short* __restrict__ h,
                                                float* __restrict__ sum, int n_nodes) {
    __shared__ float cs[CH];
    int tid = threadIdx.x;
    int c2 = (tid & 63) * 2;
    int rw = tid >> 6;       // 0..3
    if (tid < CH) cs[tid] = 0.f;
    __syncthreads();
    float a0 = 0.f, a1 = 0.f;
    for (int row = blockIdx.x * 4 + rw; row < n_nodes; row += gridDim.x * 4) {
        unsigned v = *(const unsigned*)(h + (size_t)row * CH + c2);
        a0 += __uint_as_float(v << 16);
        a1 += __uint_as_float(v & 0xffff0000u);
    }
    atomicAdd(&cs[c2], a0);
    atomicAdd(&cs[c2 + 1], a1);
    __syncthreads();
    if (tid < CH) atomicAdd(sum + tid, cs[tid]);
}

// ---------- head: mean -> 128x16 matvec -> log_softmax ----------
__global__ void k_head(const float* __restrict__ sum, const float* __restrict__ lw,
                       const float* __restrict__ lb, float* __restrict__ outp, int n_nodes) {
    __shared__ float mean[CH];
    int t = threadIdx.x;  // 128
    mean[t] = sum[t] / (float)n_nodes;
    __syncthreads();
    if (t < OUT_CH) {
        float g = lb[t];
        for (int i = 0; i < CH; ++i) g += mean[i] * lw[i * OUT_CH + t];
        float m = g;
        #pragma unroll
        for (int off = 8; off; off >>= 1) m = fmaxf(m, __shfl_xor(m, off, 16));
        float ex = expf(g - m);
        float se = ex;
        #pragma unroll
        for (int off = 8; off; off >>= 1) se += __shfl_xor(se, off, 16);
        outp[t] = g - m - logf(se);
    }
}

extern "C" void kernel_launch(void* const* d_in, const int* in_sizes, int n_in,
                              void* d_out, int out_size, void* d_ws, size_t ws_size,
                              hipStream_t stream) {
    const float* x  = (const float*)d_in[0];
    const float* W1 = (const float*)d_in[1];
    const float* q1 = (const float*)d_in[2];
    const float* k1 = (const float*)d_in[3];
    const float* b1 = (const float*)d_in[4];
    const float* W2 = (const float*)d_in[5];
    const float* q2 = (const float*)d_in[6];
    const float* k2 = (const float*)d_in[7];
    const float* b2 = (const float*)d_in[8];
    const float* lw = (const float*)d_in[9];
    const float* lb = (const float*)d_in[10];
    const int* ei   = (const int*)d_in[11];
    const int* etp  = (const int*)d_in[12];

    const int n  = in_sizes[0] / CH;
    const int ne = in_sizes[12];
    const int* esrc = ei;
    const int* edst = ei + ne;

    char* ws = (char*)d_ws;
    size_t off = 0;
    auto carve = [&](size_t bytes) -> char* {
        char* p = ws + off;
        off = (off + bytes + 255) & ~(size_t)255;
        return p;
    };
    unsigned short* xw  = (unsigned short*)carve((size_t)N_REL * n * CH * 2);
    unsigned short* xb  = (unsigned short*)carve((size_t)n * CH * 2);
    unsigned short* h1b = (unsigned short*)carve((size_t)n * CH * 2);
    unsigned short* h2b = (unsigned short*)carve((size_t)n * CH * 2);
    unsigned short* wpk = (unsigned short*)carve((size_t)N_REL * 32 * 64 * 8 * 2);
    float* sq     = (float*)carve((size_t)N_REL * n * 4);
    float* sk     = (float*)carve((size_t)N_REL * n * 4);
    float* wq     = (float*)carve(N_REL * CH * 4);
    float* wk     = (float*)carve(N_REL * CH * 4);
    int* count    = (int*)carve((size_t)n * 4);
    int* rowptr   = (int*)carve((size_t)(n + 1) * 4);
    int* rowptr_w = (int*)carve((size_t)n * 4);
    int* pe       = (int*)carve((size_t)ne * 4);
    float* sum128 = (float*)carve(CH * 4);

    hipMemsetAsync(count, 0, (size_t)n * 4, stream);
    hipMemsetAsync(sum128, 0, CH * 4, stream);

    // ---- CSR build (shared by both layers) ----
    k_hist<<<(ne + 255) / 256, 256, 0, stream>>>(edst, count, ne);
    k_scan<<<1, 1024, 0, stream>>>(count, rowptr, rowptr_w, n);
    k_scatter<<<(ne + 255) / 256, 256, 0, stream>>>(esrc, edst, etp, rowptr_w, pe, ne);

    const int wpack_threads = N_REL * 8 * 4 * 64;
    const int NW = 2048;  // 512 blocks x 4 waves

    auto run_layer = [&](const unsigned short* Xb, const float* W, const float* qv,
                         const float* kv, const float* bv, unsigned short* houtb) {
        k_wqk<<<N_REL, CH, 0, stream>>>(W, qv, kv, wq, wk);
        k_wpack<<<(wpack_threads + 255) / 256, 256, 0, stream>>>(W, wpk);
        k_gemm3<<<NW / 4, 256, 0, stream>>>(Xb, wpk, xw, n, NW);
        k_sqsk<<<(n + 3) / 4, 256, 0, stream>>>(Xb, wq, wk, sq, sk, n);
        k_attn<<<(n + 3) / 4, 256, 0, stream>>>(rowptr, pe, sq, sk, xw, bv, houtb, n);
    };

    k_cast<<<(int)(((long)n * CH / 8 + 255) / 256), 256, 0, stream>>>(x, xb, (long)n * CH);
    run_layer(xb, W1, q1, k1, b1, h1b);
    run_layer(h1b, W2, q2, k2, b2, h2b);

    k_colsum<<<256, 256, 0, stream>>>(h2b, sum128, n);
    k_head<<<1, CH, 0, stream>>>(sum128, lw, lb, (float*)d_out, n);
}

// Round 7
// 321.427 us; speedup vs baseline: 6.3405x; 1.2932x over previous
//
#include <hip/hip_runtime.h>

#define CH 128
#define N_REL 8
#define OUT_CH 16
#define NEG_SLOPE 0.2f

typedef short short8 __attribute__((ext_vector_type(8)));
typedef float f32x4 __attribute__((ext_vector_type(4)));

// ---------- helpers ----------
__device__ __forceinline__ unsigned short f2bf(float f) {  // RTN-even f32->bf16
    unsigned u = __float_as_uint(f);
    return (unsigned short)((u + 0x7fffu + ((u >> 16) & 1u)) >> 16);
}

// ---------- wq[r] = W[r] @ q, wk[r] = W[r] @ k  (tiny) ----------
__global__ void k_wqk(const float* __restrict__ W, const float* __restrict__ qv,
                      const float* __restrict__ kv, float* __restrict__ wq,
                      float* __restrict__ wk) {
    int r = blockIdx.x;       // N_REL
    int i = threadIdx.x;      // CH
    const float* row = W + ((size_t)r * CH + i) * CH;
    float aq = 0.f, ak = 0.f;
    for (int o = 0; o < CH; ++o) { float w = row[o]; aq += w * qv[o]; ak += w * kv[o]; }
    wq[r * CH + i] = aq;
    wk[r * CH + i] = ak;
}

// ---------- pack [wq|wk] columns into MFMA A-fragment order ----------
// qkf[(ks*64+lane)*8+i] = col(lane&15)[ks*32+(lane>>4)*8+i]; col j = wq[j] (j<8) else wk[j-8]
__global__ void k_qkpack(const float* __restrict__ wq, const float* __restrict__ wk,
                         unsigned short* __restrict__ qkf) {
    int tid = threadIdx.x;       // 256
    int lane = tid & 63, ks = tid >> 6;
    int j = lane & 15, g = lane >> 4;
    const float* col = (j < 8) ? (wq + j * CH) : (wk + (j - 8) * CH);
    int k0 = ks * 32 + g * 8;
    unsigned pk[4];
    #pragma unroll
    for (int p = 0; p < 4; ++p) {
        unsigned lo = f2bf(col[k0 + 2 * p]);
        unsigned hi = f2bf(col[k0 + 2 * p + 1]);
        pk[p] = lo | (hi << 16);
    }
    *(uint4*)(qkf + (size_t)tid * 8) = make_uint4(pk[0], pk[1], pk[2], pk[3]);
}

// ---------- sq/sk via MFMA: [n x 128] @ [128 x 16], wave per 16 nodes ----------
__global__ __launch_bounds__(256) void k_sqsk2(const unsigned short* __restrict__ Xb,
                                               const unsigned short* __restrict__ qkf,
                                               float* __restrict__ sq,
                                               float* __restrict__ sk, int n) {
    const int wv = threadIdx.x >> 6, lane = threadIdx.x & 63;
    const int l15 = lane & 15, g = lane >> 4;
    const int t = blockIdx.x * 4 + wv;
    const int ntiles = (n + 15) >> 4;
    if (t >= ntiles) return;

    short8 qf[4];
    #pragma unroll
    for (int ks = 0; ks < 4; ++ks)
        qf[ks] = *(const short8*)(qkf + (size_t)(ks * 64 + lane) * 8);

    int row = t * 16 + l15;
    bool ok = row < n;
    int rowc = ok ? row : n - 1;
    const unsigned short* xrow = Xb + (size_t)rowc * CH + g * 8;
    short8 xf[4];
    #pragma unroll
    for (int ks = 0; ks < 4; ++ks) xf[ks] = *(const short8*)(xrow + ks * 32);

    f32x4 dq = {0.f, 0.f, 0.f, 0.f};
    #pragma unroll
    for (int ks = 0; ks < 4; ++ks)
        dq = __builtin_amdgcn_mfma_f32_16x16x32_bf16(qf[ks], xf[ks], dq, 0, 0, 0);

    if (ok) {
        float* base = (g < 2) ? sq : sk;     // j = g*4+reg; j<8 -> sq
        int j0 = (g & 1) * 4;
        #pragma unroll
        for (int reg = 0; reg < 4; ++reg)
            base[(size_t)(j0 + reg) * n + row] = dq[reg];
    }
}

// ---------- X (fp32) -> Xb (bf16), 8 elems/thread ----------
__global__ void k_cast(const float* __restrict__ X, unsigned short* __restrict__ Xb,
                       long total) {
    long i = ((long)blockIdx.x * 256 + threadIdx.x) * 8;
    if (i >= total) return;
    float4 v0 = *(const float4*)(X + i);
    float4 v1 = *(const float4*)(X + i + 4);
    ushort4 a, b;
    a.x = f2bf(v0.x); a.y = f2bf(v0.y); a.z = f2bf(v0.z); a.w = f2bf(v0.w);
    b.x = f2bf(v1.x); b.y = f2bf(v1.y); b.z = f2bf(v1.z); b.w = f2bf(v1.w);
    *(ushort4*)(Xb + i) = a;
    *(ushort4*)(Xb + i + 4) = b;
}

// ---------- pack W[r] into A-fragment order (bf16) ----------
// Wpk[((r*8+ct)*4+ks)*64 + lane][i] = W[r][ks*32+(lane>>4)*8+i][ct*16+(lane&15)]
__global__ void k_wpack(const float* __restrict__ W, unsigned short* __restrict__ Wpk) {
    int t = blockIdx.x * 256 + threadIdx.x;
    if (t >= N_REL * 8 * 4 * 64) return;
    int lane = t & 63, ks = (t >> 6) & 3, ct = (t >> 8) & 7, r = t >> 11;
    int l15 = lane & 15, g = lane >> 4;
    const float* src = W + ((size_t)r * CH + ks * 32 + g * 8) * CH + ct * 16 + l15;
    unsigned pk[4];
    for (int p = 0; p < 4; ++p) {
        unsigned lo = f2bf(src[(2 * p) * CH]);
        unsigned hi = f2bf(src[(2 * p + 1) * CH]);
        pk[p] = lo | (hi << 16);
    }
    uint4 o = make_uint4(pk[0], pk[1], pk[2], pk[3]);
    *(uint4*)(Wpk + (size_t)t * 8) = o;
}

// ---------- XW[r] = X @ W[r] via bf16 MFMA, relation-resident W in VGPRs ----------
__global__ __launch_bounds__(256) void k_gemm3(const unsigned short* __restrict__ Xb,
                                               const unsigned short* __restrict__ Wpk,
                                               unsigned short* __restrict__ XW,
                                               int n, int nwaves) {
    const int wv = threadIdx.x >> 6, lane = threadIdx.x & 63;
    const int l15 = lane & 15, g = lane >> 4;
    const int w = blockIdx.x * 4 + wv;
    const int r = w & 7;
    const int slot = w >> 3;
    const int nslots = nwaves >> 3;
    const int ntiles = (n + 15) >> 4;

    short8 wf[8][4];
    const unsigned short* wr = Wpk + ((size_t)r * 32 * 64 + lane) * 8;
    #pragma unroll
    for (int ct = 0; ct < 8; ++ct)
        #pragma unroll
        for (int ks = 0; ks < 4; ++ks)
            wf[ct][ks] = *(const short8*)(wr + (size_t)(ct * 4 + ks) * 64 * 8);

    for (int t = slot; t < ntiles; t += nslots) {
        int row = t * 16 + l15;
        bool ok = row < n;
        int rowc = ok ? row : n - 1;
        const unsigned short* xrow = Xb + (size_t)rowc * CH + g * 8;
        short8 xf[4];
        #pragma unroll
        for (int ks = 0; ks < 4; ++ks) xf[ks] = *(const short8*)(xrow + ks * 32);
        unsigned short* orow = XW + ((size_t)r * n + row) * CH;
        #pragma unroll
        for (int ct = 0; ct < 8; ++ct) {
            f32x4 a = {0.f, 0.f, 0.f, 0.f};
            #pragma unroll
            for (int ks = 0; ks < 4; ++ks)
                a = __builtin_amdgcn_mfma_f32_16x16x32_bf16(wf[ct][ks], xf[ks], a, 0, 0, 0);
            unsigned p01, p23;
            asm("v_cvt_pk_bf16_f32 %0, %1, %2" : "=v"(p01) : "v"(a[0]), "v"(a[1]));
            asm("v_cvt_pk_bf16_f32 %0, %1, %2" : "=v"(p23) : "v"(a[2]), "v"(a[3]));
            if (ok) *(uint2*)(orow + ct * 16 + g * 4) = make_uint2(p01, p23);
        }
    }
}

// ---------- CSR build: histogram ----------
__global__ void k_hist(const int* __restrict__ dst, int* __restrict__ count, int ne) {
    int e = blockIdx.x * 256 + threadIdx.x;
    if (e >= ne) return;
    atomicAdd(count + dst[e], 1);
}

// ---------- CSR build: single-block exclusive scan (1024 threads) ----------
__global__ __launch_bounds__(1024) void k_scan(const int* __restrict__ count,
                                               int* __restrict__ rowptr,
                                               int* __restrict__ rowptr_work,
                                               int n_nodes) {
    __shared__ int wsum[16];
    __shared__ int wscan[16];
    __shared__ int carry_s;
    int tid = threadIdx.x, lane = tid & 63, w = tid >> 6;
    if (tid == 0) carry_s = 0;
    __syncthreads();
    for (int base = 0; base < n_nodes; base += 1024) {
        int i = base + tid;
        int v = (i < n_nodes) ? count[i] : 0;
        int s = v;
        #pragma unroll
        for (int off = 1; off < 64; off <<= 1) {
            int t = __shfl_up(s, off);
            if (lane >= off) s += t;
        }
        if (lane == 63) wsum[w] = s;
        __syncthreads();
        if (tid < 16) {
            int t = wsum[tid];
            #pragma unroll
            for (int off = 1; off < 16; off <<= 1) {
                int u = __shfl_up(t, off, 16);
                if ((lane & 15) >= off) t += u;
            }
            wscan[tid] = t;
        }
        __syncthreads();
        int wpref = (w == 0) ? 0 : wscan[w - 1];
        int excl = carry_s + wpref + s - v;
        if (i < n_nodes) { rowptr[i] = excl; rowptr_work[i] = excl; }
        __syncthreads();
        if (tid == 0) carry_s += wscan[15];
        __syncthreads();
    }
    if (tid == 0) rowptr[n_nodes] = carry_s;
}

// ---------- CSR build: scatter (src | et<<16 packed; src < 65536) ----------
__global__ void k_scatter(const int* __restrict__ src, const int* __restrict__ dst,
                          const int* __restrict__ et, int* __restrict__ rowptr_work,
                          int* __restrict__ pe, int ne) {
    int e = blockIdx.x * 256 + threadIdx.x;
    if (e >= ne) return;
    int pos = atomicAdd(rowptr_work + dst[e], 1);
    pe[pos] = (src[e] & 0xffff) | (et[e] << 16);
}

// ---------- fused per-node attention -> bf16 output ----------
// wave per node; gather: 4 edges/iter (g=lane>>4), 16B (8 ch) per lane (l16=lane&15)
__global__ __launch_bounds__(256) void k_attn(
    const int* __restrict__ rowptr, const int* __restrict__ pe,
    const float* __restrict__ sq, const float* __restrict__ sk,
    const unsigned short* __restrict__ XW, const float* __restrict__ bias,
    unsigned short* __restrict__ outb, int n_nodes) {
    int wid = (blockIdx.x * 256 + threadIdx.x) >> 6;
    int lane = threadIdx.x & 63;
    if (wid >= n_nodes) return;
    const int l16 = lane & 15, g16 = lane >> 4;
    int r0 = rowptr[wid], r1 = rowptr[wid + 1];
    float acc[8] = {};
    float denom = 0.f;

    if (r1 > r0) {
        float sqv = (lane < N_REL) ? sq[lane * n_nodes + wid] : 0.f;

        // pass 1: global max
        float m = -1e30f;
        for (int c0 = r0; c0 < r1; c0 += 64) {
            int j = c0 + lane;
            float a = -1e30f;
            if (j < r1) {
                int p = pe[j];
                int s = p & 0xffff, t = p >> 16;
                float av = __shfl(sqv, t) + sk[t * n_nodes + s];
                a = av >= 0.f ? av : NEG_SLOPE * av;
            }
            m = fmaxf(m, a);
        }
        #pragma unroll
        for (int off = 32; off; off >>= 1) m = fmaxf(m, __shfl_xor(m, off));

        // pass 2: exp + denom + wide gather
        for (int c0 = r0; c0 < r1; c0 += 64) {
            int j = c0 + lane;
            float ev = 0.f;
            int p = 0;
            if (j < r1) {
                p = pe[j];
                int s = p & 0xffff, t = p >> 16;
                float av = __shfl(sqv, t) + sk[t * n_nodes + s];
                av = av >= 0.f ? av : NEG_SLOPE * av;
                ev = __expf(av - m);
            }
            float evs = ev;
            #pragma unroll
            for (int off = 32; off; off >>= 1) evs += __shfl_xor(evs, off);
            denom += evs;

            int C = r1 - c0;
            if (C > 64) C = 64;
            for (int jj = 0; jj < C; jj += 4) {
                int lsel = jj + g16;                  // lane holding edge jj+g16
                float evj = __shfl(ev, lsel);         // 0 for lanes past C
                int pj = __shfl(p, lsel);
                int s = pj & 0xffff, t = pj >> 16;
                const unsigned short* row = XW + ((size_t)(t * n_nodes + s)) * CH + l16 * 8;
                uint4 v = *(const uint4*)row;
                acc[0] += evj * __uint_as_float(v.x << 16);
                acc[1] += evj * __uint_as_float(v.x & 0xffff0000u);
                acc[2] += evj * __uint_as_float(v.y << 16);
                acc[3] += evj * __uint_as_float(v.y & 0xffff0000u);
                acc[4] += evj * __uint_as_float(v.z << 16);
                acc[5] += evj * __uint_as_float(v.z & 0xffff0000u);
                acc[6] += evj * __uint_as_float(v.w << 16);
                acc[7] += evj * __uint_as_float(v.w & 0xffff0000u);
            }
        }
    }

    // combine the 4 edge-groups
    #pragma unroll
    for (int i = 0; i < 8; ++i) {
        acc[i] += __shfl_xor(acc[i], 16);
        acc[i] += __shfl_xor(acc[i], 32);
    }

    if (lane < 16) {
        float inv = denom > 0.f ? 1.f / denom : 0.f;
        unsigned pk[4];
        #pragma unroll
        for (int i = 0; i < 4; ++i) {
            float b0 = bias[l16 * 8 + 2 * i];
            float b1 = bias[l16 * 8 + 2 * i + 1];
            float o0 = acc[2 * i] * inv + b0;
            float o1 = acc[2 * i + 1] * inv + b1;
            o0 = o0 > 0.f ? o0 : 0.f;
            o1 = o1 > 0.f ? o1 : 0.f;
            pk[i] = (unsigned)f2bf(o0) | ((unsigned)f2bf(o1) << 16);
        }
        *(uint4*)(outb + (size_t)wid * CH + l16 * 8) = make_uint4(pk[0], pk[1], pk[2], pk[3]);
    }
}

// ---------- column sum over nodes (bf16 input, LDS block reduce) ----------
__global__ __launch_bounds__(256) void k_colsum(const unsigned short* __restrict__ h,
                                                float* __restrict__ sum, int n_nodes) {
    __shared__ float cs[CH];
    int tid = threadIdx.x;
    int c2 = (tid & 63) * 2;
    int rw = tid >> 6;       // 0..3
    if (tid < CH) cs[tid] = 0.f;
    __syncthreads();
    float a0 = 0.f, a1 = 0.f;
    for (int row = blockIdx.x * 4 + rw; row < n_nodes; row += gridDim.x * 4) {
        unsigned v = *(const unsigned*)(h + (size_t)row * CH + c2);
        a0 += __uint_as_float(v << 16);
        a1 += __uint_as_float(v & 0xffff0000u);
    }
    atomicAdd(&cs[c2], a0);
    atomicAdd(&cs[c2 + 1], a1);
    __syncthreads();
    if (tid < CH) atomicAdd(sum + tid, cs[tid]);
}

// ---------- head: mean -> 128x16 matvec -> log_softmax ----------
__global__ void k_head(const float* __restrict__ sum, const float* __restrict__ lw,
                       const float* __restrict__ lb, float* __restrict__ outp, int n_nodes) {
    __shared__ float mean[CH];
    int t = threadIdx.x;  // 128
    mean[t] = sum[t] / (float)n_nodes;
    __syncthreads();
    if (t < OUT_CH) {
        float g = lb[t];
        for (int i = 0; i < CH; ++i) g += mean[i] * lw[i * OUT_CH + t];
        float m = g;
        #pragma unroll
        for (int off = 8; off; off >>= 1) m = fmaxf(m, __shfl_xor(m, off, 16));
        float ex = expf(g - m);
        float se = ex;
        #pragma unroll
        for (int off = 8; off; off >>= 1) se += __shfl_xor(se, off, 16);
        outp[t] = g - m - logf(se);
    }
}

extern "C" void kernel_launch(void* const* d_in, const int* in_sizes, int n_in,
                              void* d_out, int out_size, void* d_ws, size_t ws_size,
                              hipStream_t stream) {
    const float* x  = (const float*)d_in[0];
    const float* W1 = (const float*)d_in[1];
    const float* q1 = (const float*)d_in[2];
    const float* k1 = (const float*)d_in[3];
    const float* b1 = (const float*)d_in[4];
    const float* W2 = (const float*)d_in[5];
    const float* q2 = (const float*)d_in[6];
    const float* k2 = (const float*)d_in[7];
    const float* b2 = (const float*)d_in[8];
    const float* lw = (const float*)d_in[9];
    const float* lb = (const float*)d_in[10];
    const int* ei   = (const int*)d_in[11];
    const int* etp  = (const int*)d_in[12];

    const int n  = in_sizes[0] / CH;
    const int ne = in_sizes[12];
    const int* esrc = ei;
    const int* edst = ei + ne;

    char* ws = (char*)d_ws;
    size_t off = 0;
    auto carve = [&](size_t bytes) -> char* {
        char* p = ws + off;
        off = (off + bytes + 255) & ~(size_t)255;
        return p;
    };
    unsigned short* xw  = (unsigned short*)carve((size_t)N_REL * n * CH * 2);
    unsigned short* xb  = (unsigned short*)carve((size_t)n * CH * 2);
    unsigned short* h1b = (unsigned short*)carve((size_t)n * CH * 2);
    unsigned short* h2b = (unsigned short*)carve((size_t)n * CH * 2);
    unsigned short* wpk = (unsigned short*)carve((size_t)N_REL * 32 * 64 * 8 * 2);
    unsigned short* qkf = (unsigned short*)carve((size_t)256 * 8 * 2);
    float* sq     = (float*)carve((size_t)N_REL * n * 4);
    float* sk     = (float*)carve((size_t)N_REL * n * 4);
    float* wq     = (float*)carve(N_REL * CH * 4);
    float* wk     = (float*)carve(N_REL * CH * 4);
    int* count    = (int*)carve((size_t)n * 4);
    int* rowptr   = (int*)carve((size_t)(n + 1) * 4);
    int* rowptr_w = (int*)carve((size_t)n * 4);
    int* pe       = (int*)carve((size_t)ne * 4);
    float* sum128 = (float*)carve(CH * 4);

    hipMemsetAsync(count, 0, (size_t)n * 4, stream);
    hipMemsetAsync(sum128, 0, CH * 4, stream);

    // ---- CSR build (shared by both layers) ----
    k_hist<<<(ne + 255) / 256, 256, 0, stream>>>(edst, count, ne);
    k_scan<<<1, 1024, 0, stream>>>(count, rowptr, rowptr_w, n);
    k_scatter<<<(ne + 255) / 256, 256, 0, stream>>>(esrc, edst, etp, rowptr_w, pe, ne);

    const int wpack_threads = N_REL * 8 * 4 * 64;
    const int NW = 2048;  // 512 blocks x 4 waves
    const int ntiles = (n + 15) >> 4;

    auto run_layer = [&](const unsigned short* Xb, const float* W, const float* qv,
                         const float* kv, const float* bv, unsigned short* houtb) {
        k_wqk<<<N_REL, CH, 0, stream>>>(W, qv, kv, wq, wk);
        k_wpack<<<(wpack_threads + 255) / 256, 256, 0, stream>>>(W, wpk);
        k_qkpack<<<1, 256, 0, stream>>>(wq, wk, qkf);
        k_gemm3<<<NW / 4, 256, 0, stream>>>(Xb, wpk, xw, n, NW);
        k_sqsk2<<<(ntiles + 3) / 4, 256, 0, stream>>>(Xb, qkf, sq, sk, n);
        k_attn<<<(n + 3) / 4, 256, 0, stream>>>(rowptr, pe, sq, sk, xw, bv, houtb, n);
    };

    k_cast<<<(int)(((long)n * CH / 8 + 255) / 256), 256, 0, stream>>>(x, xb, (long)n * CH);
    run_layer(xb, W1, q1, k1, b1, h1b);
    run_layer(h1b, W2, q2, k2, b2, h2b);

    k_colsum<<<256, 256, 0, stream>>>(h2b, sum128, n);
    k_head<<<1, CH, 0, stream>>>(sum128, lw, lb, (float*)d_out, n);
}

// Round 8
// 282.651 us; speedup vs baseline: 7.2103x; 1.1372x over previous
//
#include <hip/hip_runtime.h>

#define CH 128
#define N_REL 8
#define OUT_CH 16
#define NEG_SLOPE 0.2f

typedef short short8 __attribute__((ext_vector_type(8)));
typedef float f32x4 __attribute__((ext_vector_type(4)));

// ---------- helpers ----------
__device__ __forceinline__ unsigned short f2bf(float f) {  // RTN-even f32->bf16
    unsigned u = __float_as_uint(f);
    return (unsigned short)((u + 0x7fffu + ((u >> 16) & 1u)) >> 16);
}

// ---------- wq[r] = W[r] @ q, wk[r] = W[r] @ k  (tiny) ----------
__global__ void k_wqk(const float* __restrict__ W, const float* __restrict__ qv,
                      const float* __restrict__ kv, float* __restrict__ wq,
                      float* __restrict__ wk) {
    int r = blockIdx.x;       // N_REL
    int i = threadIdx.x;      // CH
    const float* row = W + ((size_t)r * CH + i) * CH;
    float aq = 0.f, ak = 0.f;
    for (int o = 0; o < CH; ++o) { float w = row[o]; aq += w * qv[o]; ak += w * kv[o]; }
    wq[r * CH + i] = aq;
    wk[r * CH + i] = ak;
}

// ---------- pack [wq|wk] columns into MFMA A-fragment order ----------
__global__ void k_qkpack(const float* __restrict__ wq, const float* __restrict__ wk,
                         unsigned short* __restrict__ qkf) {
    int tid = threadIdx.x;       // 256
    int lane = tid & 63, ks = tid >> 6;
    int j = lane & 15, g = lane >> 4;
    const float* col = (j < 8) ? (wq + j * CH) : (wk + (j - 8) * CH);
    int k0 = ks * 32 + g * 8;
    unsigned pk[4];
    #pragma unroll
    for (int p = 0; p < 4; ++p) {
        unsigned lo = f2bf(col[k0 + 2 * p]);
        unsigned hi = f2bf(col[k0 + 2 * p + 1]);
        pk[p] = lo | (hi << 16);
    }
    *(uint4*)(qkf + (size_t)tid * 8) = make_uint4(pk[0], pk[1], pk[2], pk[3]);
}

// ---------- sq/sk via MFMA: [n x 128] @ [128 x 16], wave per 16 nodes ----------
__global__ __launch_bounds__(256) void k_sqsk2(const unsigned short* __restrict__ Xb,
                                               const unsigned short* __restrict__ qkf,
                                               float* __restrict__ sq,
                                               float* __restrict__ sk, int n) {
    const int wv = threadIdx.x >> 6, lane = threadIdx.x & 63;
    const int l15 = lane & 15, g = lane >> 4;
    const int t = blockIdx.x * 4 + wv;
    const int ntiles = (n + 15) >> 4;
    if (t >= ntiles) return;

    short8 qf[4];
    #pragma unroll
    for (int ks = 0; ks < 4; ++ks)
        qf[ks] = *(const short8*)(qkf + (size_t)(ks * 64 + lane) * 8);

    int row = t * 16 + l15;
    bool ok = row < n;
    int rowc = ok ? row : n - 1;
    const unsigned short* xrow = Xb + (size_t)rowc * CH + g * 8;
    short8 xf[4];
    #pragma unroll
    for (int ks = 0; ks < 4; ++ks) xf[ks] = *(const short8*)(xrow + ks * 32);

    f32x4 dq = {0.f, 0.f, 0.f, 0.f};
    #pragma unroll
    for (int ks = 0; ks < 4; ++ks)
        dq = __builtin_amdgcn_mfma_f32_16x16x32_bf16(qf[ks], xf[ks], dq, 0, 0, 0);

    if (ok) {
        float* base = (g < 2) ? sq : sk;     // j = g*4+reg; j<8 -> sq
        int j0 = (g & 1) * 4;
        #pragma unroll
        for (int reg = 0; reg < 4; ++reg)
            base[(size_t)(j0 + reg) * n + row] = dq[reg];
    }
}

// ---------- X (fp32) -> Xb (bf16), 8 elems/thread ----------
__global__ void k_cast(const float* __restrict__ X, unsigned short* __restrict__ Xb,
                       long total) {
    long i = ((long)blockIdx.x * 256 + threadIdx.x) * 8;
    if (i >= total) return;
    float4 v0 = *(const float4*)(X + i);
    float4 v1 = *(const float4*)(X + i + 4);
    ushort4 a, b;
    a.x = f2bf(v0.x); a.y = f2bf(v0.y); a.z = f2bf(v0.z); a.w = f2bf(v0.w);
    b.x = f2bf(v1.x); b.y = f2bf(v1.y); b.z = f2bf(v1.z); b.w = f2bf(v1.w);
    *(ushort4*)(Xb + i) = a;
    *(ushort4*)(Xb + i + 4) = b;
}

// ---------- pack W[r] into A-fragment order (bf16) ----------
__global__ void k_wpack(const float* __restrict__ W, unsigned short* __restrict__ Wpk) {
    int t = blockIdx.x * 256 + threadIdx.x;
    if (t >= N_REL * 8 * 4 * 64) return;
    int lane = t & 63, ks = (t >> 6) & 3, ct = (t >> 8) & 7, r = t >> 11;
    int l15 = lane & 15, g = lane >> 4;
    const float* src = W + ((size_t)r * CH + ks * 32 + g * 8) * CH + ct * 16 + l15;
    unsigned pk[4];
    for (int p = 0; p < 4; ++p) {
        unsigned lo = f2bf(src[(2 * p) * CH]);
        unsigned hi = f2bf(src[(2 * p + 1) * CH]);
        pk[p] = lo | (hi << 16);
    }
    uint4 o = make_uint4(pk[0], pk[1], pk[2], pk[3]);
    *(uint4*)(Wpk + (size_t)t * 8) = o;
}

// ---------- XW[r] = X @ W[r] via bf16 MFMA, relation-resident W in VGPRs ----------
__global__ __launch_bounds__(256) void k_gemm3(const unsigned short* __restrict__ Xb,
                                               const unsigned short* __restrict__ Wpk,
                                               unsigned short* __restrict__ XW,
                                               int n, int nwaves) {
    const int wv = threadIdx.x >> 6, lane = threadIdx.x & 63;
    const int l15 = lane & 15, g = lane >> 4;
    const int w = blockIdx.x * 4 + wv;
    const int r = w & 7;
    const int slot = w >> 3;
    const int nslots = nwaves >> 3;
    const int ntiles = (n + 15) >> 4;

    short8 wf[8][4];
    const unsigned short* wr = Wpk + ((size_t)r * 32 * 64 + lane) * 8;
    #pragma unroll
    for (int ct = 0; ct < 8; ++ct)
        #pragma unroll
        for (int ks = 0; ks < 4; ++ks)
            wf[ct][ks] = *(const short8*)(wr + (size_t)(ct * 4 + ks) * 64 * 8);

    for (int t = slot; t < ntiles; t += nslots) {
        int row = t * 16 + l15;
        bool ok = row < n;
        int rowc = ok ? row : n - 1;
        const unsigned short* xrow = Xb + (size_t)rowc * CH + g * 8;
        short8 xf[4];
        #pragma unroll
        for (int ks = 0; ks < 4; ++ks) xf[ks] = *(const short8*)(xrow + ks * 32);
        unsigned short* orow = XW + ((size_t)r * n + row) * CH;
        #pragma unroll
        for (int ct = 0; ct < 8; ++ct) {
            f32x4 a = {0.f, 0.f, 0.f, 0.f};
            #pragma unroll
            for (int ks = 0; ks < 4; ++ks)
                a = __builtin_amdgcn_mfma_f32_16x16x32_bf16(wf[ct][ks], xf[ks], a, 0, 0, 0);
            unsigned p01, p23;
            asm("v_cvt_pk_bf16_f32 %0, %1, %2" : "=v"(p01) : "v"(a[0]), "v"(a[1]));
            asm("v_cvt_pk_bf16_f32 %0, %1, %2" : "=v"(p23) : "v"(a[2]), "v"(a[3]));
            if (ok) *(uint2*)(orow + ct * 16 + g * 4) = make_uint2(p01, p23);
        }
    }
}

// ---------- CSR build: histogram ----------
__global__ void k_hist(const int* __restrict__ dst, int* __restrict__ count, int ne) {
    int e = blockIdx.x * 256 + threadIdx.x;
    if (e >= ne) return;
    atomicAdd(count + dst[e], 1);
}

// ---------- hierarchical scan, phase 1: per-block (1024 elems) exclusive scan ----------
__global__ __launch_bounds__(256) void k_scan1(const int* __restrict__ count,
                                               int* __restrict__ rowptr,
                                               int* __restrict__ bsum, int n) {
    __shared__ int wsum[4];
    int b = blockIdx.x, tid = threadIdx.x, lane = tid & 63, w = tid >> 6;
    int i0 = b * 1024 + tid * 4;
    int v0 = 0, v1 = 0, v2 = 0, v3 = 0;
    if (i0 + 3 < n) {
        int4 v = *(const int4*)(count + i0);
        v0 = v.x; v1 = v.y; v2 = v.z; v3 = v.w;
    } else {
        if (i0 < n) v0 = count[i0];
        if (i0 + 1 < n) v1 = count[i0 + 1];
        if (i0 + 2 < n) v2 = count[i0 + 2];
        if (i0 + 3 < n) v3 = count[i0 + 3];
    }
    int t1 = v0 + v1, t2 = t1 + v2, t3 = t2 + v3;   // quad prefix (inclusive)
    int s = t3;
    #pragma unroll
    for (int off = 1; off < 64; off <<= 1) {
        int t = __shfl_up(s, off);
        if (lane >= off) s += t;
    }
    if (lane == 63) wsum[w] = s;
    __syncthreads();
    int wpre = 0;
    #pragma unroll
    for (int i = 0; i < 4; ++i) wpre += (i < w) ? wsum[i] : 0;
    int excl = wpre + s - t3;
    if (i0 < n) rowptr[i0] = excl;
    if (i0 + 1 < n) rowptr[i0 + 1] = excl + v0;
    if (i0 + 2 < n) rowptr[i0 + 2] = excl + t1;
    if (i0 + 3 < n) rowptr[i0 + 3] = excl + t2;
    if (tid == 0) bsum[b] = wsum[0] + wsum[1] + wsum[2] + wsum[3];
}

// ---------- scan phase 2: exclusive scan of block sums (1 wave, carry loop) ----------
__global__ void k_scan2(int* __restrict__ bsum, int* __restrict__ total, int nb) {
    int lane = threadIdx.x;   // 64
    int carry = 0;
    for (int base = 0; base < nb; base += 64) {
        int i = base + lane;
        int v = (i < nb) ? bsum[i] : 0;
        int s = v;
        #pragma unroll
        for (int off = 1; off < 64; off <<= 1) {
            int t = __shfl_up(s, off);
            if (lane >= off) s += t;
        }
        if (i < nb) bsum[i] = carry + s - v;
        carry += __shfl(s, 63);
    }
    if (lane == 0) *total = carry;
}

// ---------- scan phase 3: add block offsets; emit rowptr_work and rowptr[n] ----------
__global__ __launch_bounds__(256) void k_scan3(int* __restrict__ rowptr,
                                               int* __restrict__ rowptr_work,
                                               const int* __restrict__ bsum,
                                               const int* __restrict__ total, int n) {
    int b = blockIdx.x;
    int i0 = b * 1024 + threadIdx.x * 4;
    int add = bsum[b];
    #pragma unroll
    for (int j = 0; j < 4; ++j) {
        int i = i0 + j;
        if (i < n) {
            int v = rowptr[i] + add;
            rowptr[i] = v;
            rowptr_work[i] = v;
        }
    }
    if (b == 0 && threadIdx.x == 0) rowptr[n] = *total;
}

// ---------- CSR build: scatter (src | et<<16 packed; src < 65536) ----------
__global__ void k_scatter(const int* __restrict__ src, const int* __restrict__ dst,
                          const int* __restrict__ et, int* __restrict__ rowptr_work,
                          int* __restrict__ pe, int ne) {
    int e = blockIdx.x * 256 + threadIdx.x;
    if (e >= ne) return;
    int pos = atomicAdd(rowptr_work + dst[e], 1);
    pe[pos] = (src[e] & 0xffff) | (et[e] << 16);
}

// ---------- fused per-node attention -> bf16 output ----------
__global__ __launch_bounds__(256) void k_attn(
    const int* __restrict__ rowptr, const int* __restrict__ pe,
    const float* __restrict__ sq, const float* __restrict__ sk,
    const unsigned short* __restrict__ XW, const float* __restrict__ bias,
    unsigned short* __restrict__ outb, int n_nodes) {
    int wid = (blockIdx.x * 256 + threadIdx.x) >> 6;
    int lane = threadIdx.x & 63;
    if (wid >= n_nodes) return;
    const int l16 = lane & 15, g16 = lane >> 4;
    int r0 = rowptr[wid], r1 = rowptr[wid + 1];
    float acc[8] = {};
    float denom = 0.f;

    if (r1 > r0) {
        float sqv = (lane < N_REL) ? sq[lane * n_nodes + wid] : 0.f;

        float m = -1e30f;
        for (int c0 = r0; c0 < r1; c0 += 64) {
            int j = c0 + lane;
            float a = -1e30f;
            if (j < r1) {
                int p = pe[j];
                int s = p & 0xffff, t = p >> 16;
                float av = __shfl(sqv, t) + sk[t * n_nodes + s];
                a = av >= 0.f ? av : NEG_SLOPE * av;
            }
            m = fmaxf(m, a);
        }
        #pragma unroll
        for (int off = 32; off; off >>= 1) m = fmaxf(m, __shfl_xor(m, off));

        for (int c0 = r0; c0 < r1; c0 += 64) {
            int j = c0 + lane;
            float ev = 0.f;
            int p = 0;
            if (j < r1) {
                p = pe[j];
                int s = p & 0xffff, t = p >> 16;
                float av = __shfl(sqv, t) + sk[t * n_nodes + s];
                av = av >= 0.f ? av : NEG_SLOPE * av;
                ev = __expf(av - m);
            }
            float evs = ev;
            #pragma unroll
            for (int off = 32; off; off >>= 1) evs += __shfl_xor(evs, off);
            denom += evs;

            int C = r1 - c0;
            if (C > 64) C = 64;
            for (int jj = 0; jj < C; jj += 4) {
                int lsel = jj + g16;
                float evj = __shfl(ev, lsel);
                int pj = __shfl(p, lsel);
                int s = pj & 0xffff, t = pj >> 16;
                const unsigned short* row = XW + ((size_t)(t * n_nodes + s)) * CH + l16 * 8;
                uint4 v = *(const uint4*)row;
                acc[0] += evj * __uint_as_float(v.x << 16);
                acc[1] += evj * __uint_as_float(v.x & 0xffff0000u);
                acc[2] += evj * __uint_as_float(v.y << 16);
                acc[3] += evj * __uint_as_float(v.y & 0xffff0000u);
                acc[4] += evj * __uint_as_float(v.z << 16);
                acc[5] += evj * __uint_as_float(v.z & 0xffff0000u);
                acc[6] += evj * __uint_as_float(v.w << 16);
                acc[7] += evj * __uint_as_float(v.w & 0xffff0000u);
            }
        }
    }

    #pragma unroll
    for (int i = 0; i < 8; ++i) {
        acc[i] += __shfl_xor(acc[i], 16);
        acc[i] += __shfl_xor(acc[i], 32);
    }

    if (lane < 16) {
        float inv = denom > 0.f ? 1.f / denom : 0.f;
        unsigned pk[4];
        #pragma unroll
        for (int i = 0; i < 4; ++i) {
            float b0 = bias[l16 * 8 + 2 * i];
            float b1 = bias[l16 * 8 + 2 * i + 1];
            float o0 = acc[2 * i] * inv + b0;
            float o1 = acc[2 * i + 1] * inv + b1;
            o0 = o0 > 0.f ? o0 : 0.f;
            o1 = o1 > 0.f ? o1 : 0.f;
            pk[i] = (unsigned)f2bf(o0) | ((unsigned)f2bf(o1) << 16);
        }
        *(uint4*)(outb + (size_t)wid * CH + l16 * 8) = make_uint4(pk[0], pk[1], pk[2], pk[3]);
    }
}

// ---------- column sum over nodes (bf16 input, LDS block reduce) ----------
__global__ __launch_bounds__(256) void k_colsum(const unsigned short* __restrict__ h,
                                                float* __restrict__ sum, int n_nodes) {
    __shared__ float cs[CH];
    int tid = threadIdx.x;
    int c2 = (tid & 63) * 2;
    int rw = tid >> 6;
    if (tid < CH) cs[tid] = 0.f;
    __syncthreads();
    float a0 = 0.f, a1 = 0.f;
    for (int row = blockIdx.x * 4 + rw; row < n_nodes; row += gridDim.x * 4) {
        unsigned v = *(const unsigned*)(h + (size_t)row * CH + c2);
        a0 += __uint_as_float(v << 16);
        a1 += __uint_as_float(v & 0xffff0000u);
    }
    atomicAdd(&cs[c2], a0);
    atomicAdd(&cs[c2 + 1], a1);
    __syncthreads();
    if (tid < CH) atomicAdd(sum + tid, cs[tid]);
}

// ---------- head: mean -> 128x16 matvec -> log_softmax ----------
__global__ void k_head(const float* __restrict__ sum, const float* __restrict__ lw,
                       const float* __restrict__ lb, float* __restrict__ outp, int n_nodes) {
    __shared__ float mean[CH];
    int t = threadIdx.x;  // 128
    mean[t] = sum[t] / (float)n_nodes;
    __syncthreads();
    if (t < OUT_CH) {
        float g = lb[t];
        for (int i = 0; i < CH; ++i) g += mean[i] * lw[i * OUT_CH + t];
        float m = g;
        #pragma unroll
        for (int off = 8; off; off >>= 1) m = fmaxf(m, __shfl_xor(m, off, 16));
        float ex = expf(g - m);
        float se = ex;
        #pragma unroll
        for (int off = 8; off; off >>= 1) se += __shfl_xor(se, off, 16);
        outp[t] = g - m - logf(se);
    }
}

extern "C" void kernel_launch(void* const* d_in, const int* in_sizes, int n_in,
                              void* d_out, int out_size, void* d_ws, size_t ws_size,
                              hipStream_t stream) {
    const float* x  = (const float*)d_in[0];
    const float* W1 = (const float*)d_in[1];
    const float* q1 = (const float*)d_in[2];
    const float* k1 = (const float*)d_in[3];
    const float* b1 = (const float*)d_in[4];
    const float* W2 = (const float*)d_in[5];
    const float* q2 = (const float*)d_in[6];
    const float* k2 = (const float*)d_in[7];
    const float* b2 = (const float*)d_in[8];
    const float* lw = (const float*)d_in[9];
    const float* lb = (const float*)d_in[10];
    const int* ei   = (const int*)d_in[11];
    const int* etp  = (const int*)d_in[12];

    const int n  = in_sizes[0] / CH;
    const int ne = in_sizes[12];
    const int* esrc = ei;
    const int* edst = ei + ne;

    char* ws = (char*)d_ws;
    size_t off = 0;
    auto carve = [&](size_t bytes) -> char* {
        char* p = ws + off;
        off = (off + bytes + 255) & ~(size_t)255;
        return p;
    };
    unsigned short* xw  = (unsigned short*)carve((size_t)N_REL * n * CH * 2);
    unsigned short* xb  = (unsigned short*)carve((size_t)n * CH * 2);
    unsigned short* h1b = (unsigned short*)carve((size_t)n * CH * 2);
    unsigned short* h2b = (unsigned short*)carve((size_t)n * CH * 2);
    unsigned short* wpk = (unsigned short*)carve((size_t)N_REL * 32 * 64 * 8 * 2);
    unsigned short* qkf = (unsigned short*)carve((size_t)256 * 8 * 2);
    float* sq     = (float*)carve((size_t)N_REL * n * 4);
    float* sk     = (float*)carve((size_t)N_REL * n * 4);
    float* wq     = (float*)carve(N_REL * CH * 4);
    float* wk     = (float*)carve(N_REL * CH * 4);
    int* count    = (int*)carve((size_t)n * 4);
    int* rowptr   = (int*)carve((size_t)(n + 1) * 4);
    int* rowptr_w = (int*)carve((size_t)n * 4);
    int* pe       = (int*)carve((size_t)ne * 4);
    int* bsum     = (int*)carve((size_t)256 * 4);
    int* total    = (int*)carve(4);
    float* sum128 = (float*)carve(CH * 4);

    hipMemsetAsync(count, 0, (size_t)n * 4, stream);
    hipMemsetAsync(sum128, 0, CH * 4, stream);

    // ---- CSR build (shared by both layers) ----
    const int nbscan = (n + 1023) / 1024;
    k_hist<<<(ne + 255) / 256, 256, 0, stream>>>(edst, count, ne);
    k_scan1<<<nbscan, 256, 0, stream>>>(count, rowptr, bsum, n);
    k_scan2<<<1, 64, 0, stream>>>(bsum, total, nbscan);
    k_scan3<<<nbscan, 256, 0, stream>>>(rowptr, rowptr_w, bsum, total, n);
    k_scatter<<<(ne + 255) / 256, 256, 0, stream>>>(esrc, edst, etp, rowptr_w, pe, ne);

    const int wpack_threads = N_REL * 8 * 4 * 64;
    const int NW = 2048;  // 512 blocks x 4 waves
    const int ntiles = (n + 15) >> 4;

    auto run_layer = [&](const unsigned short* Xb, const float* W, const float* qv,
                         const float* kv, const float* bv, unsigned short* houtb) {
        k_wqk<<<N_REL, CH, 0, stream>>>(W, qv, kv, wq, wk);
        k_wpack<<<(wpack_threads + 255) / 256, 256, 0, stream>>>(W, wpk);
        k_qkpack<<<1, 256, 0, stream>>>(wq, wk, qkf);
        k_gemm3<<<NW / 4, 256, 0, stream>>>(Xb, wpk, xw, n, NW);
        k_sqsk2<<<(ntiles + 3) / 4, 256, 0, stream>>>(Xb, qkf, sq, sk, n);
        k_attn<<<(n + 3) / 4, 256, 0, stream>>>(rowptr, pe, sq, sk, xw, bv, houtb, n);
    };

    k_cast<<<(int)(((long)n * CH / 8 + 255) / 256), 256, 0, stream>>>(x, xb, (long)n * CH);
    run_layer(xb, W1, q1, k1, b1, h1b);
    run_layer(h1b, W2, q2, k2, b2, h2b);

    k_colsum<<<256, 256, 0, stream>>>(h2b, sum128, n);
    k_head<<<1, CH, 0, stream>>>(sum128, lw, lb, (float*)d_out, n);
}

// Round 9
// 254.246 us; speedup vs baseline: 8.0159x; 1.1117x over previous
//
#include <hip/hip_runtime.h>

#define CH 128
#define N_REL 8
#define OUT_CH 16
#define NEG_SLOPE 0.2f

typedef short short8 __attribute__((ext_vector_type(8)));
typedef float f32x4 __attribute__((ext_vector_type(4)));

// ---------- helpers ----------
__device__ __forceinline__ unsigned short f2bf(float f) {  // RTN-even f32->bf16
    unsigned u = __float_as_uint(f);
    return (unsigned short)((u + 0x7fffu + ((u >> 16) & 1u)) >> 16);
}

// ================= device bodies (verbatim from verified R8 kernels) =================

__device__ __forceinline__ void dev_cast(const float* __restrict__ X,
                                         unsigned short* __restrict__ Xb,
                                         long total, int b, int tid) {
    long i = ((long)b * 256 + tid) * 8;
    if (i >= total) return;
    float4 v0 = *(const float4*)(X + i);
    float4 v1 = *(const float4*)(X + i + 4);
    ushort4 a, c;
    a.x = f2bf(v0.x); a.y = f2bf(v0.y); a.z = f2bf(v0.z); a.w = f2bf(v0.w);
    c.x = f2bf(v1.x); c.y = f2bf(v1.y); c.z = f2bf(v1.z); c.w = f2bf(v1.w);
    *(ushort4*)(Xb + i) = a;
    *(ushort4*)(Xb + i + 4) = c;
}

__device__ __forceinline__ void dev_wqk(const float* __restrict__ W,
                                        const float* __restrict__ qv,
                                        const float* __restrict__ kv,
                                        float* __restrict__ wq, float* __restrict__ wk,
                                        int rb, int tid) {
    int r = rb * 2 + (tid >> 7);
    int i = tid & 127;
    const float* row = W + ((size_t)r * CH + i) * CH;
    float aq = 0.f, ak = 0.f;
    for (int o = 0; o < CH; ++o) { float w = row[o]; aq += w * qv[o]; ak += w * kv[o]; }
    wq[r * CH + i] = aq;
    wk[r * CH + i] = ak;
}

__device__ __forceinline__ void dev_wpack(const float* __restrict__ W,
                                          unsigned short* __restrict__ Wpk, int t) {
    int lane = t & 63, ks = (t >> 6) & 3, ct = (t >> 8) & 7, r = t >> 11;
    int l15 = lane & 15, g = lane >> 4;
    const float* src = W + ((size_t)r * CH + ks * 32 + g * 8) * CH + ct * 16 + l15;
    unsigned pk[4];
    #pragma unroll
    for (int p = 0; p < 4; ++p) {
        unsigned lo = f2bf(src[(2 * p) * CH]);
        unsigned hi = f2bf(src[(2 * p + 1) * CH]);
        pk[p] = lo | (hi << 16);
    }
    *(uint4*)(Wpk + (size_t)t * 8) = make_uint4(pk[0], pk[1], pk[2], pk[3]);
}

__device__ __forceinline__ void dev_qkpack(const float* __restrict__ wq,
                                           const float* __restrict__ wk,
                                           unsigned short* __restrict__ qkf, int tid) {
    int lane = tid & 63, ks = tid >> 6;
    int j = lane & 15, g = lane >> 4;
    const float* col = (j < 8) ? (wq + j * CH) : (wk + (j - 8) * CH);
    int k0 = ks * 32 + g * 8;
    unsigned pk[4];
    #pragma unroll
    for (int p = 0; p < 4; ++p) {
        unsigned lo = f2bf(col[k0 + 2 * p]);
        unsigned hi = f2bf(col[k0 + 2 * p + 1]);
        pk[p] = lo | (hi << 16);
    }
    *(uint4*)(qkf + (size_t)tid * 8) = make_uint4(pk[0], pk[1], pk[2], pk[3]);
}

// ================= fused small kernels =================

__global__ void k_cast_hist(const float* __restrict__ X, unsigned short* __restrict__ Xb,
                            long total, const int* __restrict__ dst,
                            int* __restrict__ count, int ne, int nb_cast) {
    int b = blockIdx.x, tid = threadIdx.x;
    if (b < nb_cast) {
        dev_cast(X, Xb, total, b, tid);
    } else {
        int e = (b - nb_cast) * 256 + tid;
        if (e < ne) atomicAdd(count + dst[e], 1);
    }
}

__global__ __launch_bounds__(256) void k_scan1_wqk(const int* __restrict__ count,
                                                   int* __restrict__ rowptr,
                                                   int* __restrict__ bsum, int n, int nbscan,
                                                   const float* __restrict__ W,
                                                   const float* __restrict__ qv,
                                                   const float* __restrict__ kv,
                                                   float* __restrict__ wq,
                                                   float* __restrict__ wk) {
    int b = blockIdx.x, tid = threadIdx.x;
    if (b >= nbscan) { dev_wqk(W, qv, kv, wq, wk, b - nbscan, tid); return; }
    __shared__ int wsum[4];
    int lane = tid & 63, w = tid >> 6;
    int i0 = b * 1024 + tid * 4;
    int v0 = 0, v1 = 0, v2 = 0, v3 = 0;
    if (i0 + 3 < n) {
        int4 v = *(const int4*)(count + i0);
        v0 = v.x; v1 = v.y; v2 = v.z; v3 = v.w;
    } else {
        if (i0 < n) v0 = count[i0];
        if (i0 + 1 < n) v1 = count[i0 + 1];
        if (i0 + 2 < n) v2 = count[i0 + 2];
        if (i0 + 3 < n) v3 = count[i0 + 3];
    }
    int t1 = v0 + v1, t2 = t1 + v2, t3 = t2 + v3;
    int s = t3;
    #pragma unroll
    for (int off = 1; off < 64; off <<= 1) {
        int t = __shfl_up(s, off);
        if (lane >= off) s += t;
    }
    if (lane == 63) wsum[w] = s;
    __syncthreads();
    int wpre = 0;
    #pragma unroll
    for (int i = 0; i < 4; ++i) wpre += (i < w) ? wsum[i] : 0;
    int excl = wpre + s - t3;
    if (i0 < n) rowptr[i0] = excl;
    if (i0 + 1 < n) rowptr[i0 + 1] = excl + v0;
    if (i0 + 2 < n) rowptr[i0 + 2] = excl + t1;
    if (i0 + 3 < n) rowptr[i0 + 3] = excl + t2;
    if (tid == 0) bsum[b] = wsum[0] + wsum[1] + wsum[2] + wsum[3];
}

__global__ __launch_bounds__(256) void k_scan2_wprep(int* __restrict__ bsum,
                                                     int* __restrict__ total, int nb,
                                                     const float* __restrict__ W,
                                                     unsigned short* __restrict__ Wpk,
                                                     const float* __restrict__ wq,
                                                     const float* __restrict__ wk,
                                                     unsigned short* __restrict__ qkf) {
    int b = blockIdx.x, tid = threadIdx.x;
    if (b == 0) {
        if (tid >= 64) return;
        int lane = tid;
        int carry = 0;
        for (int base = 0; base < nb; base += 64) {
            int i = base + lane;
            int v = (i < nb) ? bsum[i] : 0;
            int s = v;
            #pragma unroll
            for (int off = 1; off < 64; off <<= 1) {
                int t = __shfl_up(s, off);
                if (lane >= off) s += t;
            }
            if (i < nb) bsum[i] = carry + s - v;
            carry += __shfl(s, 63);
        }
        if (lane == 0) *total = carry;
    } else if (b <= 64) {
        dev_wpack(W, Wpk, (b - 1) * 256 + tid);
    } else {
        dev_qkpack(wq, wk, qkf, tid);
    }
}

__global__ __launch_bounds__(256) void k_scan3(int* __restrict__ rowptr,
                                               int* __restrict__ rowptr_work,
                                               const int* __restrict__ bsum,
                                               const int* __restrict__ total, int n) {
    int b = blockIdx.x;
    int i0 = b * 1024 + threadIdx.x * 4;
    int add = bsum[b];
    #pragma unroll
    for (int j = 0; j < 4; ++j) {
        int i = i0 + j;
        if (i < n) {
            int v = rowptr[i] + add;
            rowptr[i] = v;
            rowptr_work[i] = v;
        }
    }
    if (b == 0 && threadIdx.x == 0) rowptr[n] = *total;
}

// ================= fat kernel: gemm3 || sqsk2 || scatter =================

__global__ __launch_bounds__(256) void k_fat(
    const unsigned short* __restrict__ Xb, const unsigned short* __restrict__ Wpk,
    const unsigned short* __restrict__ qkf, unsigned short* __restrict__ XW,
    float* __restrict__ sq, float* __restrict__ sk, int n, int nwaves,
    int nb_gemm, int nb_sqsk,
    const int* __restrict__ esrc, const int* __restrict__ edst,
    const int* __restrict__ etp, int* __restrict__ rowptr_work,
    int* __restrict__ pe, int ne) {
    const int b = blockIdx.x, tid = threadIdx.x;
    const int wv = tid >> 6, lane = tid & 63;
    const int l15 = lane & 15, g = lane >> 4;
    const int ntiles = (n + 15) >> 4;

    if (b < nb_gemm) {
        // ---- gemm3: relation-resident W in VGPRs ----
        const int w = b * 4 + wv;
        const int r = w & 7;
        const int slot = w >> 3;
        const int nslots = nwaves >> 3;

        short8 wf[8][4];
        const unsigned short* wr = Wpk + ((size_t)r * 32 * 64 + lane) * 8;
        #pragma unroll
        for (int ct = 0; ct < 8; ++ct)
            #pragma unroll
            for (int ks = 0; ks < 4; ++ks)
                wf[ct][ks] = *(const short8*)(wr + (size_t)(ct * 4 + ks) * 64 * 8);

        for (int t = slot; t < ntiles; t += nslots) {
            int row = t * 16 + l15;
            bool ok = row < n;
            int rowc = ok ? row : n - 1;
            const unsigned short* xrow = Xb + (size_t)rowc * CH + g * 8;
            short8 xf[4];
            #pragma unroll
            for (int ks = 0; ks < 4; ++ks) xf[ks] = *(const short8*)(xrow + ks * 32);
            unsigned short* orow = XW + ((size_t)r * n + row) * CH;
            #pragma unroll
            for (int ct = 0; ct < 8; ++ct) {
                f32x4 a = {0.f, 0.f, 0.f, 0.f};
                #pragma unroll
                for (int ks = 0; ks < 4; ++ks)
                    a = __builtin_amdgcn_mfma_f32_16x16x32_bf16(wf[ct][ks], xf[ks], a, 0, 0, 0);
                unsigned p01, p23;
                asm("v_cvt_pk_bf16_f32 %0, %1, %2" : "=v"(p01) : "v"(a[0]), "v"(a[1]));
                asm("v_cvt_pk_bf16_f32 %0, %1, %2" : "=v"(p23) : "v"(a[2]), "v"(a[3]));
                if (ok) *(uint2*)(orow + ct * 16 + g * 4) = make_uint2(p01, p23);
            }
        }
    } else if (b < nb_gemm + nb_sqsk) {
        // ---- sqsk2 ----
        const int t = (b - nb_gemm) * 4 + wv;
        if (t >= ntiles) return;
        short8 qf[4];
        #pragma unroll
        for (int ks = 0; ks < 4; ++ks)
            qf[ks] = *(const short8*)(qkf + (size_t)(ks * 64 + lane) * 8);
        int row = t * 16 + l15;
        bool ok = row < n;
        int rowc = ok ? row : n - 1;
        const unsigned short* xrow = Xb + (size_t)rowc * CH + g * 8;
        short8 xf[4];
        #pragma unroll
        for (int ks = 0; ks < 4; ++ks) xf[ks] = *(const short8*)(xrow + ks * 32);
        f32x4 dq = {0.f, 0.f, 0.f, 0.f};
        #pragma unroll
        for (int ks = 0; ks < 4; ++ks)
            dq = __builtin_amdgcn_mfma_f32_16x16x32_bf16(qf[ks], xf[ks], dq, 0, 0, 0);
        if (ok) {
            float* base = (g < 2) ? sq : sk;
            int j0 = (g & 1) * 4;
            #pragma unroll
            for (int reg = 0; reg < 4; ++reg)
                base[(size_t)(j0 + reg) * n + row] = dq[reg];
        }
    } else {
        // ---- scatter ----
        int e = (b - nb_gemm - nb_sqsk) * 256 + tid;
        if (e >= ne) return;
        int pos = atomicAdd(rowptr_work + edst[e], 1);
        pe[pos] = (esrc[e] & 0xffff) | (etp[e] << 16);
    }
}

// ================= attn (+ optional next-layer wqk) =================

__global__ __launch_bounds__(256) void k_attn_wqk(
    const int* __restrict__ rowptr, const int* __restrict__ pe,
    const float* __restrict__ sq, const float* __restrict__ sk,
    const unsigned short* __restrict__ XW, const float* __restrict__ bias,
    unsigned short* __restrict__ outb, int n_nodes,
    const float* __restrict__ Wn, const float* __restrict__ qn,
    const float* __restrict__ kn, float* __restrict__ wqn,
    float* __restrict__ wkn, int nb_wqk) {
    int b = blockIdx.x;
    if (b < nb_wqk) { dev_wqk(Wn, qn, kn, wqn, wkn, b, threadIdx.x); return; }
    int wid = ((b - nb_wqk) * 256 + threadIdx.x) >> 6;
    int lane = threadIdx.x & 63;
    if (wid >= n_nodes) return;
    const int l16 = lane & 15, g16 = lane >> 4;
    int r0 = rowptr[wid], r1 = rowptr[wid + 1];
    float acc[8] = {};
    float denom = 0.f;

    if (r1 > r0) {
        float sqv = (lane < N_REL) ? sq[lane * n_nodes + wid] : 0.f;

        float m = -1e30f;
        for (int c0 = r0; c0 < r1; c0 += 64) {
            int j = c0 + lane;
            float a = -1e30f;
            if (j < r1) {
                int p = pe[j];
                int s = p & 0xffff, t = p >> 16;
                float av = __shfl(sqv, t) + sk[t * n_nodes + s];
                a = av >= 0.f ? av : NEG_SLOPE * av;
            }
            m = fmaxf(m, a);
        }
        #pragma unroll
        for (int off = 32; off; off >>= 1) m = fmaxf(m, __shfl_xor(m, off));

        for (int c0 = r0; c0 < r1; c0 += 64) {
            int j = c0 + lane;
            float ev = 0.f;
            int p = 0;
            if (j < r1) {
                p = pe[j];
                int s = p & 0xffff, t = p >> 16;
                float av = __shfl(sqv, t) + sk[t * n_nodes + s];
                av = av >= 0.f ? av : NEG_SLOPE * av;
                ev = __expf(av - m);
            }
            float evs = ev;
            #pragma unroll
            for (int off = 32; off; off >>= 1) evs += __shfl_xor(evs, off);
            denom += evs;

            int C = r1 - c0;
            if (C > 64) C = 64;
            for (int jj = 0; jj < C; jj += 4) {
                int lsel = jj + g16;
                float evj = __shfl(ev, lsel);
                int pj = __shfl(p, lsel);
                int s = pj & 0xffff, t = pj >> 16;
                const unsigned short* row = XW + ((size_t)(t * n_nodes + s)) * CH + l16 * 8;
                uint4 v = *(const uint4*)row;
                acc[0] += evj * __uint_as_float(v.x << 16);
                acc[1] += evj * __uint_as_float(v.x & 0xffff0000u);
                acc[2] += evj * __uint_as_float(v.y << 16);
                acc[3] += evj * __uint_as_float(v.y & 0xffff0000u);
                acc[4] += evj * __uint_as_float(v.z << 16);
                acc[5] += evj * __uint_as_float(v.z & 0xffff0000u);
                acc[6] += evj * __uint_as_float(v.w << 16);
                acc[7] += evj * __uint_as_float(v.w & 0xffff0000u);
            }
        }
    }

    #pragma unroll
    for (int i = 0; i < 8; ++i) {
        acc[i] += __shfl_xor(acc[i], 16);
        acc[i] += __shfl_xor(acc[i], 32);
    }

    if (lane < 16) {
        float inv = denom > 0.f ? 1.f / denom : 0.f;
        unsigned pk[4];
        #pragma unroll
        for (int i = 0; i < 4; ++i) {
            float b0 = bias[l16 * 8 + 2 * i];
            float b1 = bias[l16 * 8 + 2 * i + 1];
            float o0 = acc[2 * i] * inv + b0;
            float o1 = acc[2 * i + 1] * inv + b1;
            o0 = o0 > 0.f ? o0 : 0.f;
            o1 = o1 > 0.f ? o1 : 0.f;
            pk[i] = (unsigned)f2bf(o0) | ((unsigned)f2bf(o1) << 16);
        }
        *(uint4*)(outb + (size_t)wid * CH + l16 * 8) = make_uint4(pk[0], pk[1], pk[2], pk[3]);
    }
}

// ================= layer-2 W prep (wpack || qkpack) =================

__global__ __launch_bounds__(256) void k_wprep2(const float* __restrict__ W,
                                                unsigned short* __restrict__ Wpk,
                                                const float* __restrict__ wq,
                                                const float* __restrict__ wk,
                                                unsigned short* __restrict__ qkf) {
    int b = blockIdx.x, tid = threadIdx.x;
    if (b < 64) dev_wpack(W, Wpk, b * 256 + tid);
    else dev_qkpack(wq, wk, qkf, tid);
}

// ================= tail =================

__global__ __launch_bounds__(256) void k_colsum(const unsigned short* __restrict__ h,
                                                float* __restrict__ sum, int n_nodes) {
    __shared__ float cs[CH];
    int tid = threadIdx.x;
    int c2 = (tid & 63) * 2;
    int rw = tid >> 6;
    if (tid < CH) cs[tid] = 0.f;
    __syncthreads();
    float a0 = 0.f, a1 = 0.f;
    for (int row = blockIdx.x * 4 + rw; row < n_nodes; row += gridDim.x * 4) {
        unsigned v = *(const unsigned*)(h + (size_t)row * CH + c2);
        a0 += __uint_as_float(v << 16);
        a1 += __uint_as_float(v & 0xffff0000u);
    }
    atomicAdd(&cs[c2], a0);
    atomicAdd(&cs[c2 + 1], a1);
    __syncthreads();
    if (tid < CH) atomicAdd(sum + tid, cs[tid]);
}

__global__ void k_head(const float* __restrict__ sum, const float* __restrict__ lw,
                       const float* __restrict__ lb, float* __restrict__ outp, int n_nodes) {
    __shared__ float mean[CH];
    int t = threadIdx.x;  // 128
    mean[t] = sum[t] / (float)n_nodes;
    __syncthreads();
    if (t < OUT_CH) {
        float g = lb[t];
        for (int i = 0; i < CH; ++i) g += mean[i] * lw[i * OUT_CH + t];
        float m = g;
        #pragma unroll
        for (int off = 8; off; off >>= 1) m = fmaxf(m, __shfl_xor(m, off, 16));
        float ex = expf(g - m);
        float se = ex;
        #pragma unroll
        for (int off = 8; off; off >>= 1) se += __shfl_xor(se, off, 16);
        outp[t] = g - m - logf(se);
    }
}

extern "C" void kernel_launch(void* const* d_in, const int* in_sizes, int n_in,
                              void* d_out, int out_size, void* d_ws, size_t ws_size,
                              hipStream_t stream) {
    const float* x  = (const float*)d_in[0];
    const float* W1 = (const float*)d_in[1];
    const float* q1 = (const float*)d_in[2];
    const float* k1 = (const float*)d_in[3];
    const float* b1 = (const float*)d_in[4];
    const float* W2 = (const float*)d_in[5];
    const float* q2 = (const float*)d_in[6];
    const float* k2 = (const float*)d_in[7];
    const float* b2 = (const float*)d_in[8];
    const float* lw = (const float*)d_in[9];
    const float* lb = (const float*)d_in[10];
    const int* ei   = (const int*)d_in[11];
    const int* etp  = (const int*)d_in[12];

    const int n  = in_sizes[0] / CH;
    const int ne = in_sizes[12];
    const int* esrc = ei;
    const int* edst = ei + ne;

    char* ws = (char*)d_ws;
    size_t off = 0;
    auto carve = [&](size_t bytes) -> char* {
        char* p = ws + off;
        off = (off + bytes + 255) & ~(size_t)255;
        return p;
    };
    unsigned short* xw  = (unsigned short*)carve((size_t)N_REL * n * CH * 2);
    unsigned short* xb  = (unsigned short*)carve((size_t)n * CH * 2);
    unsigned short* h1b = (unsigned short*)carve((size_t)n * CH * 2);
    unsigned short* h2b = (unsigned short*)carve((size_t)n * CH * 2);
    unsigned short* wpk = (unsigned short*)carve((size_t)N_REL * 32 * 64 * 8 * 2);
    unsigned short* qkf = (unsigned short*)carve((size_t)256 * 8 * 2);
    float* sq     = (float*)carve((size_t)N_REL * n * 4);
    float* sk     = (float*)carve((size_t)N_REL * n * 4);
    float* wq     = (float*)carve(N_REL * CH * 4);
    float* wk     = (float*)carve(N_REL * CH * 4);
    int* count    = (int*)carve((size_t)n * 4);
    int* rowptr   = (int*)carve((size_t)(n + 1) * 4);
    int* rowptr_w = (int*)carve((size_t)n * 4);
    int* pe       = (int*)carve((size_t)ne * 4);
    int* bsum     = (int*)carve((size_t)256 * 4);
    int* total    = (int*)carve(4);
    float* sum128 = (float*)carve(CH * 4);

    hipMemsetAsync(count, 0, (size_t)n * 4, stream);
    hipMemsetAsync(sum128, 0, CH * 4, stream);

    const int nbscan = (n + 1023) / 1024;
    const int nb_cast = (int)(((long)n * CH / 8 + 255) / 256);
    const int nb_hist = (ne + 255) / 256;
    const int NW = 2048;
    const int nb_gemm = NW / 4;                       // 512
    const int ntiles = (n + 15) >> 4;
    const int nb_sqsk = (ntiles + 3) / 4;             // 782
    const int nb_scat = (ne + 255) / 256;             // 2344
    const int nb_attn = (n + 3) / 4;                  // 12500

    // cast || hist
    k_cast_hist<<<nb_cast + nb_hist, 256, 0, stream>>>(x, xb, (long)n * CH, edst, count, ne, nb_cast);
    // scan1 || wqk(L1)
    k_scan1_wqk<<<nbscan + 4, 256, 0, stream>>>(count, rowptr, bsum, n, nbscan, W1, q1, k1, wq, wk);
    // scan2 || wpack(L1) || qkpack(L1)
    k_scan2_wprep<<<66, 256, 0, stream>>>(bsum, total, nbscan, W1, wpk, wq, wk, qkf);
    k_scan3<<<nbscan, 256, 0, stream>>>(rowptr, rowptr_w, bsum, total, n);
    // layer 1: gemm || sqsk || scatter
    k_fat<<<nb_gemm + nb_sqsk + nb_scat, 256, 0, stream>>>(xb, wpk, qkf, xw, sq, sk, n, NW,
                                                           nb_gemm, nb_sqsk,
                                                           esrc, edst, etp, rowptr_w, pe, ne);
    // attn(L1) || wqk(L2)
    k_attn_wqk<<<4 + nb_attn, 256, 0, stream>>>(rowptr, pe, sq, sk, xw, b1, h1b, n,
                                                W2, q2, k2, wq, wk, 4);
    // wpack(L2) || qkpack(L2)
    k_wprep2<<<65, 256, 0, stream>>>(W2, wpk, wq, wk, qkf);
    // layer 2: gemm || sqsk (no scatter)
    k_fat<<<nb_gemm + nb_sqsk, 256, 0, stream>>>(h1b, wpk, qkf, xw, sq, sk, n, NW,
                                                 nb_gemm, nb_sqsk,
                                                 esrc, edst, etp, rowptr_w, pe, 0);
    // attn(L2)
    k_attn_wqk<<<nb_attn, 256, 0, stream>>>(rowptr, pe, sq, sk, xw, b2, h2b, n,
                                            (const float*)nullptr, (const float*)nullptr,
                                            (const float*)nullptr, (float*)nullptr,
                                            (float*)nullptr, 0);

    k_colsum<<<256, 256, 0, stream>>>(h2b, sum128, n);
    k_head<<<1, CH, 0, stream>>>(sum128, lw, lb, (float*)d_out, n);
}

// Round 10
// 248.013 us; speedup vs baseline: 8.2174x; 1.0251x over previous
//
#include <hip/hip_runtime.h>

#define CH 128
#define N_REL 8
#define OUT_CH 16
#define NEG_SLOPE 0.2f

typedef short short8 __attribute__((ext_vector_type(8)));
typedef float f32x4 __attribute__((ext_vector_type(4)));

// ---------- helpers ----------
__device__ __forceinline__ unsigned short f2bf(float f) {  // RTN-even f32->bf16
    unsigned u = __float_as_uint(f);
    return (unsigned short)((u + 0x7fffu + ((u >> 16) & 1u)) >> 16);
}

// ================= device bodies =================

__device__ __forceinline__ void dev_cast(const float* __restrict__ X,
                                         unsigned short* __restrict__ Xb,
                                         long total, int b, int tid) {
    long i = ((long)b * 256 + tid) * 8;
    if (i >= total) return;
    float4 v0 = *(const float4*)(X + i);
    float4 v1 = *(const float4*)(X + i + 4);
    ushort4 a, c;
    a.x = f2bf(v0.x); a.y = f2bf(v0.y); a.z = f2bf(v0.z); a.w = f2bf(v0.w);
    c.x = f2bf(v1.x); c.y = f2bf(v1.y); c.z = f2bf(v1.z); c.w = f2bf(v1.w);
    *(ushort4*)(Xb + i) = a;
    *(ushort4*)(Xb + i + 4) = c;
}

__device__ __forceinline__ void dev_wqk(const float* __restrict__ W,
                                        const float* __restrict__ qv,
                                        const float* __restrict__ kv,
                                        float* __restrict__ wq, float* __restrict__ wk,
                                        int rb, int tid) {
    int r = rb * 2 + (tid >> 7);
    int i = tid & 127;
    const float* row = W + ((size_t)r * CH + i) * CH;
    float aq = 0.f, ak = 0.f;
    for (int o = 0; o < CH; ++o) { float w = row[o]; aq += w * qv[o]; ak += w * kv[o]; }
    wq[r * CH + i] = aq;
    wk[r * CH + i] = ak;
}

__device__ __forceinline__ void dev_wpack(const float* __restrict__ W,
                                          unsigned short* __restrict__ Wpk, int t) {
    int lane = t & 63, ks = (t >> 6) & 3, ct = (t >> 8) & 7, r = t >> 11;
    int l15 = lane & 15, g = lane >> 4;
    const float* src = W + ((size_t)r * CH + ks * 32 + g * 8) * CH + ct * 16 + l15;
    unsigned pk[4];
    #pragma unroll
    for (int p = 0; p < 4; ++p) {
        unsigned lo = f2bf(src[(2 * p) * CH]);
        unsigned hi = f2bf(src[(2 * p + 1) * CH]);
        pk[p] = lo | (hi << 16);
    }
    *(uint4*)(Wpk + (size_t)t * 8) = make_uint4(pk[0], pk[1], pk[2], pk[3]);
}

__device__ __forceinline__ void dev_qkpack(const float* __restrict__ wq,
                                           const float* __restrict__ wk,
                                           unsigned short* __restrict__ qkf, int tid) {
    int lane = tid & 63, ks = tid >> 6;
    int j = lane & 15, g = lane >> 4;
    const float* col = (j < 8) ? (wq + j * CH) : (wk + (j - 8) * CH);
    int k0 = ks * 32 + g * 8;
    unsigned pk[4];
    #pragma unroll
    for (int p = 0; p < 4; ++p) {
        unsigned lo = f2bf(col[k0 + 2 * p]);
        unsigned hi = f2bf(col[k0 + 2 * p + 1]);
        pk[p] = lo | (hi << 16);
    }
    *(uint4*)(qkf + (size_t)tid * 8) = make_uint4(pk[0], pk[1], pk[2], pk[3]);
}

// ================= fused small kernels =================

__global__ void k_cast_hist(const float* __restrict__ X, unsigned short* __restrict__ Xb,
                            long total, const int* __restrict__ dst,
                            int* __restrict__ count, int ne, int nb_cast) {
    int b = blockIdx.x, tid = threadIdx.x;
    if (b < nb_cast) {
        dev_cast(X, Xb, total, b, tid);
    } else {
        int e = (b - nb_cast) * 256 + tid;
        if (e < ne) atomicAdd(count + dst[e], 1);
    }
}

__global__ __launch_bounds__(256) void k_scan1_wqk(const int* __restrict__ count,
                                                   int* __restrict__ rowptr,
                                                   int* __restrict__ bsum, int n, int nbscan,
                                                   const float* __restrict__ W,
                                                   const float* __restrict__ qv,
                                                   const float* __restrict__ kv,
                                                   float* __restrict__ wq,
                                                   float* __restrict__ wk) {
    int b = blockIdx.x, tid = threadIdx.x;
    if (b >= nbscan) { dev_wqk(W, qv, kv, wq, wk, b - nbscan, tid); return; }
    __shared__ int wsum[4];
    int lane = tid & 63, w = tid >> 6;
    int i0 = b * 1024 + tid * 4;
    int v0 = 0, v1 = 0, v2 = 0, v3 = 0;
    if (i0 + 3 < n) {
        int4 v = *(const int4*)(count + i0);
        v0 = v.x; v1 = v.y; v2 = v.z; v3 = v.w;
    } else {
        if (i0 < n) v0 = count[i0];
        if (i0 + 1 < n) v1 = count[i0 + 1];
        if (i0 + 2 < n) v2 = count[i0 + 2];
        if (i0 + 3 < n) v3 = count[i0 + 3];
    }
    int t1 = v0 + v1, t2 = t1 + v2, t3 = t2 + v3;
    int s = t3;
    #pragma unroll
    for (int off = 1; off < 64; off <<= 1) {
        int t = __shfl_up(s, off);
        if (lane >= off) s += t;
    }
    if (lane == 63) wsum[w] = s;
    __syncthreads();
    int wpre = 0;
    #pragma unroll
    for (int i = 0; i < 4; ++i) wpre += (i < w) ? wsum[i] : 0;
    int excl = wpre + s - t3;
    if (i0 < n) rowptr[i0] = excl;
    if (i0 + 1 < n) rowptr[i0 + 1] = excl + v0;
    if (i0 + 2 < n) rowptr[i0 + 2] = excl + t1;
    if (i0 + 3 < n) rowptr[i0 + 3] = excl + t2;
    if (tid == 0) bsum[b] = wsum[0] + wsum[1] + wsum[2] + wsum[3];
}

__global__ __launch_bounds__(256) void k_scan2_wprep(int* __restrict__ bsum,
                                                     int* __restrict__ total, int nb,
                                                     const float* __restrict__ W,
                                                     unsigned short* __restrict__ Wpk,
                                                     const float* __restrict__ wq,
                                                     const float* __restrict__ wk,
                                                     unsigned short* __restrict__ qkf) {
    int b = blockIdx.x, tid = threadIdx.x;
    if (b == 0) {
        if (tid >= 64) return;
        int lane = tid;
        int carry = 0;
        for (int base = 0; base < nb; base += 64) {
            int i = base + lane;
            int v = (i < nb) ? bsum[i] : 0;
            int s = v;
            #pragma unroll
            for (int off = 1; off < 64; off <<= 1) {
                int t = __shfl_up(s, off);
                if (lane >= off) s += t;
            }
            if (i < nb) bsum[i] = carry + s - v;
            carry += __shfl(s, 63);
        }
        if (lane == 0) *total = carry;
    } else if (b <= 64) {
        dev_wpack(W, Wpk, (b - 1) * 256 + tid);
    } else {
        dev_qkpack(wq, wk, qkf, tid);
    }
}

__global__ __launch_bounds__(256) void k_scan3(int* __restrict__ rowptr,
                                               int* __restrict__ rowptr_work,
                                               const int* __restrict__ bsum,
                                               const int* __restrict__ total, int n) {
    int b = blockIdx.x;
    int i0 = b * 1024 + threadIdx.x * 4;
    int add = bsum[b];
    #pragma unroll
    for (int j = 0; j < 4; ++j) {
        int i = i0 + j;
        if (i < n) {
            int v = rowptr[i] + add;
            rowptr[i] = v;
            rowptr_work[i] = v;
        }
    }
    if (b == 0 && threadIdx.x == 0) rowptr[n] = *total;
}

// ================= fat kernel: gemm3 || sqsk2 || scatter =================

__global__ __launch_bounds__(256, 1) void k_fat(
    const unsigned short* __restrict__ Xb, const unsigned short* __restrict__ Wpk,
    const unsigned short* __restrict__ qkf, unsigned short* __restrict__ XW,
    float* __restrict__ sq, float* __restrict__ sk, int n, int nwaves,
    int nb_gemm, int nb_sqsk,
    const int* __restrict__ esrc, const int* __restrict__ edst,
    const int* __restrict__ etp, int* __restrict__ rowptr_work,
    int* __restrict__ pe, int ne) {
    const int b = blockIdx.x, tid = threadIdx.x;
    const int wv = tid >> 6, lane = tid & 63;
    const int l15 = lane & 15, g = lane >> 4;
    const int ntiles = (n + 15) >> 4;

    if (b < nb_gemm) {
        // ---- gemm3: relation-resident W in VGPRs (pinned against remat) ----
        const int w = b * 4 + wv;
        const int r = w & 7;
        const int slot = w >> 3;
        const int nslots = nwaves >> 3;

        short8 wf[8][4];
        const unsigned short* wr = Wpk + ((size_t)r * 32 * 64 + lane) * 8;
        #pragma unroll
        for (int ct = 0; ct < 8; ++ct)
            #pragma unroll
            for (int ks = 0; ks < 4; ++ks) {
                wf[ct][ks] = *(const short8*)(wr + (size_t)(ct * 4 + ks) * 64 * 8);
                asm volatile("" : "+v"(wf[ct][ks]));  // pin: forbid rematerialization
            }

        for (int t = slot; t < ntiles; t += nslots) {
            int row = t * 16 + l15;
            bool ok = row < n;
            int rowc = ok ? row : n - 1;
            const unsigned short* xrow = Xb + (size_t)rowc * CH + g * 8;
            short8 xf[4];
            #pragma unroll
            for (int ks = 0; ks < 4; ++ks) xf[ks] = *(const short8*)(xrow + ks * 32);
            unsigned short* orow = XW + ((size_t)r * n + row) * CH;
            #pragma unroll
            for (int ct = 0; ct < 8; ++ct) {
                f32x4 a = {0.f, 0.f, 0.f, 0.f};
                #pragma unroll
                for (int ks = 0; ks < 4; ++ks)
                    a = __builtin_amdgcn_mfma_f32_16x16x32_bf16(wf[ct][ks], xf[ks], a, 0, 0, 0);
                unsigned p01, p23;
                asm("v_cvt_pk_bf16_f32 %0, %1, %2" : "=v"(p01) : "v"(a[0]), "v"(a[1]));
                asm("v_cvt_pk_bf16_f32 %0, %1, %2" : "=v"(p23) : "v"(a[2]), "v"(a[3]));
                if (ok) *(uint2*)(orow + ct * 16 + g * 4) = make_uint2(p01, p23);
            }
        }
    } else if (b < nb_gemm + nb_sqsk) {
        // ---- sqsk2 ----
        const int t = (b - nb_gemm) * 4 + wv;
        if (t >= ntiles) return;
        short8 qf[4];
        #pragma unroll
        for (int ks = 0; ks < 4; ++ks)
            qf[ks] = *(const short8*)(qkf + (size_t)(ks * 64 + lane) * 8);
        int row = t * 16 + l15;
        bool ok = row < n;
        int rowc = ok ? row : n - 1;
        const unsigned short* xrow = Xb + (size_t)rowc * CH + g * 8;
        short8 xf[4];
        #pragma unroll
        for (int ks = 0; ks < 4; ++ks) xf[ks] = *(const short8*)(xrow + ks * 32);
        f32x4 dq = {0.f, 0.f, 0.f, 0.f};
        #pragma unroll
        for (int ks = 0; ks < 4; ++ks)
            dq = __builtin_amdgcn_mfma_f32_16x16x32_bf16(qf[ks], xf[ks], dq, 0, 0, 0);
        if (ok) {
            float* base = (g < 2) ? sq : sk;
            int j0 = (g & 1) * 4;
            #pragma unroll
            for (int reg = 0; reg < 4; ++reg)
                base[(size_t)(j0 + reg) * n + row] = dq[reg];
        }
    } else {
        // ---- scatter ----
        int e = (b - nb_gemm - nb_sqsk) * 256 + tid;
        if (e >= ne) return;
        int pos = atomicAdd(rowptr_work + edst[e], 1);
        pe[pos] = (esrc[e] & 0xffff) | (etp[e] << 16);
    }
}

// ================= attn (+ optional next-layer wqk) =================

__global__ __launch_bounds__(256) void k_attn_wqk(
    const int* __restrict__ rowptr, const int* __restrict__ pe,
    const float* __restrict__ sq, const float* __restrict__ sk,
    const unsigned short* __restrict__ XW, const float* __restrict__ bias,
    unsigned short* __restrict__ outb, int n_nodes,
    const float* __restrict__ Wn, const float* __restrict__ qn,
    const float* __restrict__ kn, float* __restrict__ wqn,
    float* __restrict__ wkn, int nb_wqk) {
    int b = blockIdx.x;
    if (b < nb_wqk) { dev_wqk(Wn, qn, kn, wqn, wkn, b, threadIdx.x); return; }
    int wid = ((b - nb_wqk) * 256 + threadIdx.x) >> 6;
    int lane = threadIdx.x & 63;
    if (wid >= n_nodes) return;
    const int l16 = lane & 15, g16 = lane >> 4;
    int r0 = rowptr[wid], r1 = rowptr[wid + 1];
    float acc[8] = {};
    float denom = 0.f;

    if (r1 > r0) {
        float sqv = (lane < N_REL) ? sq[lane * n_nodes + wid] : 0.f;

        float m = -1e30f;
        for (int c0 = r0; c0 < r1; c0 += 64) {
            int j = c0 + lane;
            float a = -1e30f;
            if (j < r1) {
                int p = pe[j];
                int s = p & 0xffff, t = p >> 16;
                float av = __shfl(sqv, t) + sk[t * n_nodes + s];
                a = av >= 0.f ? av : NEG_SLOPE * av;
            }
            m = fmaxf(m, a);
        }
        #pragma unroll
        for (int off = 32; off; off >>= 1) m = fmaxf(m, __shfl_xor(m, off));

        for (int c0 = r0; c0 < r1; c0 += 64) {
            int j = c0 + lane;
            float ev = 0.f;
            int p = 0;
            if (j < r1) {
                p = pe[j];
                int s = p & 0xffff, t = p >> 16;
                float av = __shfl(sqv, t) + sk[t * n_nodes + s];
                av = av >= 0.f ? av : NEG_SLOPE * av;
                ev = __expf(av - m);
            }
            float evs = ev;
            #pragma unroll
            for (int off = 32; off; off >>= 1) evs += __shfl_xor(evs, off);
            denom += evs;

            int C = r1 - c0;
            if (C > 64) C = 64;
            for (int jj = 0; jj < C; jj += 4) {
                int lsel = jj + g16;
                float evj = __shfl(ev, lsel);
                int pj = __shfl(p, lsel);
                int s = pj & 0xffff, t = pj >> 16;
                const unsigned short* row = XW + ((size_t)(t * n_nodes + s)) * CH + l16 * 8;
                uint4 v = *(const uint4*)row;
                acc[0] += evj * __uint_as_float(v.x << 16);
                acc[1] += evj * __uint_as_float(v.x & 0xffff0000u);
                acc[2] += evj * __uint_as_float(v.y << 16);
                acc[3] += evj * __uint_as_float(v.y & 0xffff0000u);
                acc[4] += evj * __uint_as_float(v.z << 16);
                acc[5] += evj * __uint_as_float(v.z & 0xffff0000u);
                acc[6] += evj * __uint_as_float(v.w << 16);
                acc[7] += evj * __uint_as_float(v.w & 0xffff0000u);
            }
        }
    }

    #pragma unroll
    for (int i = 0; i < 8; ++i) {
        acc[i] += __shfl_xor(acc[i], 16);
        acc[i] += __shfl_xor(acc[i], 32);
    }

    if (lane < 16) {
        float inv = denom > 0.f ? 1.f / denom : 0.f;
        unsigned pk[4];
        #pragma unroll
        for (int i = 0; i < 4; ++i) {
            float b0 = bias[l16 * 8 + 2 * i];
            float b1 = bias[l16 * 8 + 2 * i + 1];
            float o0 = acc[2 * i] * inv + b0;
            float o1 = acc[2 * i + 1] * inv + b1;
            o0 = o0 > 0.f ? o0 : 0.f;
            o1 = o1 > 0.f ? o1 : 0.f;
            pk[i] = (unsigned)f2bf(o0) | ((unsigned)f2bf(o1) << 16);
        }
        *(uint4*)(outb + (size_t)wid * CH + l16 * 8) = make_uint4(pk[0], pk[1], pk[2], pk[3]);
    }
}

// ================= layer-2 W prep (wpack || qkpack) =================

__global__ __launch_bounds__(256) void k_wprep2(const float* __restrict__ W,
                                                unsigned short* __restrict__ Wpk,
                                                const float* __restrict__ wq,
                                                const float* __restrict__ wk,
                                                unsigned short* __restrict__ qkf) {
    int b = blockIdx.x, tid = threadIdx.x;
    if (b < 64) dev_wpack(W, Wpk, b * 256 + tid);
    else dev_qkpack(wq, wk, qkf, tid);
}

// ================= tail =================

__global__ __launch_bounds__(256) void k_colsum(const unsigned short* __restrict__ h,
                                                float* __restrict__ sum, int n_nodes) {
    __shared__ float cs[CH];
    int tid = threadIdx.x;
    int c2 = (tid & 63) * 2;
    int rw = tid >> 6;
    if (tid < CH) cs[tid] = 0.f;
    __syncthreads();
    float a0 = 0.f, a1 = 0.f;
    for (int row = blockIdx.x * 4 + rw; row < n_nodes; row += gridDim.x * 4) {
        unsigned v = *(const unsigned*)(h + (size_t)row * CH + c2);
        a0 += __uint_as_float(v << 16);
        a1 += __uint_as_float(v & 0xffff0000u);
    }
    atomicAdd(&cs[c2], a0);
    atomicAdd(&cs[c2 + 1], a1);
    __syncthreads();
    if (tid < CH) atomicAdd(sum + tid, cs[tid]);
}

__global__ void k_head(const float* __restrict__ sum, const float* __restrict__ lw,
                       const float* __restrict__ lb, float* __restrict__ outp, int n_nodes) {
    __shared__ float mean[CH];
    int t = threadIdx.x;  // 128
    mean[t] = sum[t] / (float)n_nodes;
    __syncthreads();
    if (t < OUT_CH) {
        float g = lb[t];
        for (int i = 0; i < CH; ++i) g += mean[i] * lw[i * OUT_CH + t];
        float m = g;
        #pragma unroll
        for (int off = 8; off; off >>= 1) m = fmaxf(m, __shfl_xor(m, off, 16));
        float ex = expf(g - m);
        float se = ex;
        #pragma unroll
        for (int off = 8; off; off >>= 1) se += __shfl_xor(se, off, 16);
        outp[t] = g - m - logf(se);
    }
}

extern "C" void kernel_launch(void* const* d_in, const int* in_sizes, int n_in,
                              void* d_out, int out_size, void* d_ws, size_t ws_size,
                              hipStream_t stream) {
    const float* x  = (const float*)d_in[0];
    const float* W1 = (const float*)d_in[1];
    const float* q1 = (const float*)d_in[2];
    const float* k1 = (const float*)d_in[3];
    const float* b1 = (const float*)d_in[4];
    const float* W2 = (const float*)d_in[5];
    const float* q2 = (const float*)d_in[6];
    const float* k2 = (const float*)d_in[7];
    const float* b2 = (const float*)d_in[8];
    const float* lw = (const float*)d_in[9];
    const float* lb = (const float*)d_in[10];
    const int* ei   = (const int*)d_in[11];
    const int* etp  = (const int*)d_in[12];

    const int n  = in_sizes[0] / CH;
    const int ne = in_sizes[12];
    const int* esrc = ei;
    const int* edst = ei + ne;

    char* ws = (char*)d_ws;
    size_t off = 0;
    auto carve = [&](size_t bytes) -> char* {
        char* p = ws + off;
        off = (off + bytes + 255) & ~(size_t)255;
        return p;
    };
    unsigned short* xw  = (unsigned short*)carve((size_t)N_REL * n * CH * 2);
    unsigned short* xb  = (unsigned short*)carve((size_t)n * CH * 2);
    unsigned short* h1b = (unsigned short*)carve((size_t)n * CH * 2);
    unsigned short* h2b = (unsigned short*)carve((size_t)n * CH * 2);
    unsigned short* wpk = (unsigned short*)carve((size_t)N_REL * 32 * 64 * 8 * 2);
    unsigned short* qkf = (unsigned short*)carve((size_t)256 * 8 * 2);
    float* sq     = (float*)carve((size_t)N_REL * n * 4);
    float* sk     = (float*)carve((size_t)N_REL * n * 4);
    float* wq     = (float*)carve(N_REL * CH * 4);
    float* wk     = (float*)carve(N_REL * CH * 4);
    int* count    = (int*)carve((size_t)n * 4);
    int* rowptr   = (int*)carve((size_t)(n + 1) * 4);
    int* rowptr_w = (int*)carve((size_t)n * 4);
    int* pe       = (int*)carve((size_t)ne * 4);
    int* bsum     = (int*)carve((size_t)256 * 4);
    int* total    = (int*)carve(4);
    float* sum128 = (float*)carve(CH * 4);

    hipMemsetAsync(count, 0, (size_t)n * 4, stream);
    hipMemsetAsync(sum128, 0, CH * 4, stream);

    const int nbscan = (n + 1023) / 1024;
    const int nb_cast = (int)(((long)n * CH / 8 + 255) / 256);
    const int nb_hist = (ne + 255) / 256;
    const int NW = 2048;
    const int nb_gemm = NW / 4;                       // 512
    const int ntiles = (n + 15) >> 4;
    const int nb_sqsk = (ntiles + 3) / 4;             // 782
    const int nb_scat = (ne + 255) / 256;             // 2344
    const int nb_attn = (n + 3) / 4;                  // 12500

    // cast || hist
    k_cast_hist<<<nb_cast + nb_hist, 256, 0, stream>>>(x, xb, (long)n * CH, edst, count, ne, nb_cast);
    // scan1 || wqk(L1)
    k_scan1_wqk<<<nbscan + 4, 256, 0, stream>>>(count, rowptr, bsum, n, nbscan, W1, q1, k1, wq, wk);
    // scan2 || wpack(L1) || qkpack(L1)
    k_scan2_wprep<<<66, 256, 0, stream>>>(bsum, total, nbscan, W1, wpk, wq, wk, qkf);
    k_scan3<<<nbscan, 256, 0, stream>>>(rowptr, rowptr_w, bsum, total, n);
    // layer 1: gemm || sqsk || scatter
    k_fat<<<nb_gemm + nb_sqsk + nb_scat, 256, 0, stream>>>(xb, wpk, qkf, xw, sq, sk, n, NW,
                                                           nb_gemm, nb_sqsk,
                                                           esrc, edst, etp, rowptr_w, pe, ne);
    // attn(L1) || wqk(L2)
    k_attn_wqk<<<4 + nb_attn, 256, 0, stream>>>(rowptr, pe, sq, sk, xw, b1, h1b, n,
                                                W2, q2, k2, wq, wk, 4);
    // wpack(L2) || qkpack(L2)
    k_wprep2<<<65, 256, 0, stream>>>(W2, wpk, wq, wk, qkf);
    // layer 2: gemm || sqsk (no scatter)
    k_fat<<<nb_gemm + nb_sqsk, 256, 0, stream>>>(h1b, wpk, qkf, xw, sq, sk, n, NW,
                                                 nb_gemm, nb_sqsk,
                                                 esrc, edst, etp, rowptr_w, pe, 0);
    // attn(L2)
    k_attn_wqk<<<nb_attn, 256, 0, stream>>>(rowptr, pe, sq, sk, xw, b2, h2b, n,
                                            (const float*)nullptr, (const float*)nullptr,
                                            (const float*)nullptr, (float*)nullptr,
                                            (float*)nullptr, 0);

    k_colsum<<<256, 256, 0, stream>>>(h2b, sum128, n);
    k_head<<<1, CH, 0, stream>>>(sum128, lw, lb, (float*)d_out, n);
}

// Round 11
// 247.231 us; speedup vs baseline: 8.2433x; 1.0032x over previous
//
#include <hip/hip_runtime.h>

#define CH 128
#define N_REL 8
#define OUT_CH 16
#define NEG_SLOPE 0.2f

typedef short short8 __attribute__((ext_vector_type(8)));
typedef float f32x4 __attribute__((ext_vector_type(4)));

// ---------- helpers ----------
__device__ __forceinline__ unsigned short f2bf(float f) {  // RTN-even f32->bf16
    unsigned u = __float_as_uint(f);
    return (unsigned short)((u + 0x7fffu + ((u >> 16) & 1u)) >> 16);
}

// ================= device bodies =================

__device__ __forceinline__ void dev_cast(const float* __restrict__ X,
                                         unsigned short* __restrict__ Xb,
                                         long total, int b, int tid) {
    long i = ((long)b * 256 + tid) * 8;
    if (i >= total) return;
    float4 v0 = *(const float4*)(X + i);
    float4 v1 = *(const float4*)(X + i + 4);
    ushort4 a, c;
    a.x = f2bf(v0.x); a.y = f2bf(v0.y); a.z = f2bf(v0.z); a.w = f2bf(v0.w);
    c.x = f2bf(v1.x); c.y = f2bf(v1.y); c.z = f2bf(v1.z); c.w = f2bf(v1.w);
    *(ushort4*)(Xb + i) = a;
    *(ushort4*)(Xb + i + 4) = c;
}

__device__ __forceinline__ void dev_wqk(const float* __restrict__ W,
                                        const float* __restrict__ qv,
                                        const float* __restrict__ kv,
                                        float* __restrict__ wq, float* __restrict__ wk,
                                        int rb, int tid) {
    int r = rb * 2 + (tid >> 7);
    int i = tid & 127;
    const float* row = W + ((size_t)r * CH + i) * CH;
    float aq = 0.f, ak = 0.f;
    for (int o = 0; o < CH; ++o) { float w = row[o]; aq += w * qv[o]; ak += w * kv[o]; }
    wq[r * CH + i] = aq;
    wk[r * CH + i] = ak;
}

__device__ __forceinline__ void dev_wpack(const float* __restrict__ W,
                                          unsigned short* __restrict__ Wpk, int t) {
    int lane = t & 63, ks = (t >> 6) & 3, ct = (t >> 8) & 7, r = t >> 11;
    int l15 = lane & 15, g = lane >> 4;
    const float* src = W + ((size_t)r * CH + ks * 32 + g * 8) * CH + ct * 16 + l15;
    unsigned pk[4];
    #pragma unroll
    for (int p = 0; p < 4; ++p) {
        unsigned lo = f2bf(src[(2 * p) * CH]);
        unsigned hi = f2bf(src[(2 * p + 1) * CH]);
        pk[p] = lo | (hi << 16);
    }
    *(uint4*)(Wpk + (size_t)t * 8) = make_uint4(pk[0], pk[1], pk[2], pk[3]);
}

__device__ __forceinline__ void dev_qkpack(const float* __restrict__ wq,
                                           const float* __restrict__ wk,
                                           unsigned short* __restrict__ qkf, int tid) {
    int lane = tid & 63, ks = tid >> 6;
    int j = lane & 15, g = lane >> 4;
    const float* col = (j < 8) ? (wq + j * CH) : (wk + (j - 8) * CH);
    int k0 = ks * 32 + g * 8;
    unsigned pk[4];
    #pragma unroll
    for (int p = 0; p < 4; ++p) {
        unsigned lo = f2bf(col[k0 + 2 * p]);
        unsigned hi = f2bf(col[k0 + 2 * p + 1]);
        pk[p] = lo | (hi << 16);
    }
    *(uint4*)(qkf + (size_t)tid * 8) = make_uint4(pk[0], pk[1], pk[2], pk[3]);
}

// ================= fused small kernels =================

__global__ void k_cast_hist(const float* __restrict__ X, unsigned short* __restrict__ Xb,
                            long total, const int* __restrict__ dst,
                            int* __restrict__ count, int ne, int nb_cast) {
    int b = blockIdx.x, tid = threadIdx.x;
    if (b < nb_cast) {
        dev_cast(X, Xb, total, b, tid);
    } else {
        int e = (b - nb_cast) * 256 + tid;
        if (e < ne) atomicAdd(count + dst[e], 1);
    }
}

__global__ __launch_bounds__(256) void k_scan1_wqk(const int* __restrict__ count,
                                                   int* __restrict__ rowptr,
                                                   int* __restrict__ bsum, int n, int nbscan,
                                                   const float* __restrict__ W,
                                                   const float* __restrict__ qv,
                                                   const float* __restrict__ kv,
                                                   float* __restrict__ wq,
                                                   float* __restrict__ wk) {
    int b = blockIdx.x, tid = threadIdx.x;
    if (b >= nbscan) { dev_wqk(W, qv, kv, wq, wk, b - nbscan, tid); return; }
    __shared__ int wsum[4];
    int lane = tid & 63, w = tid >> 6;
    int i0 = b * 1024 + tid * 4;
    int v0 = 0, v1 = 0, v2 = 0, v3 = 0;
    if (i0 + 3 < n) {
        int4 v = *(const int4*)(count + i0);
        v0 = v.x; v1 = v.y; v2 = v.z; v3 = v.w;
    } else {
        if (i0 < n) v0 = count[i0];
        if (i0 + 1 < n) v1 = count[i0 + 1];
        if (i0 + 2 < n) v2 = count[i0 + 2];
        if (i0 + 3 < n) v3 = count[i0 + 3];
    }
    int t1 = v0 + v1, t2 = t1 + v2, t3 = t2 + v3;
    int s = t3;
    #pragma unroll
    for (int off = 1; off < 64; off <<= 1) {
        int t = __shfl_up(s, off);
        if (lane >= off) s += t;
    }
    if (lane == 63) wsum[w] = s;
    __syncthreads();
    int wpre = 0;
    #pragma unroll
    for (int i = 0; i < 4; ++i) wpre += (i < w) ? wsum[i] : 0;
    int excl = wpre + s - t3;
    if (i0 < n) rowptr[i0] = excl;
    if (i0 + 1 < n) rowptr[i0 + 1] = excl + v0;
    if (i0 + 2 < n) rowptr[i0 + 2] = excl + t1;
    if (i0 + 3 < n) rowptr[i0 + 3] = excl + t2;
    if (tid == 0) bsum[b] = wsum[0] + wsum[1] + wsum[2] + wsum[3];
}

__global__ __launch_bounds__(256) void k_scan2_wprep(int* __restrict__ bsum,
                                                     int* __restrict__ total, int nb,
                                                     const float* __restrict__ W,
                                                     unsigned short* __restrict__ Wpk,
                                                     const float* __restrict__ wq,
                                                     const float* __restrict__ wk,
                                                     unsigned short* __restrict__ qkf) {
    int b = blockIdx.x, tid = threadIdx.x;
    if (b == 0) {
        if (tid >= 64) return;
        int lane = tid;
        int carry = 0;
        for (int base = 0; base < nb; base += 64) {
            int i = base + lane;
            int v = (i < nb) ? bsum[i] : 0;
            int s = v;
            #pragma unroll
            for (int off = 1; off < 64; off <<= 1) {
                int t = __shfl_up(s, off);
                if (lane >= off) s += t;
            }
            if (i < nb) bsum[i] = carry + s - v;
            carry += __shfl(s, 63);
        }
        if (lane == 0) *total = carry;
    } else if (b <= 64) {
        dev_wpack(W, Wpk, (b - 1) * 256 + tid);
    } else {
        dev_qkpack(wq, wk, qkf, tid);
    }
}

__global__ __launch_bounds__(256) void k_scan3(int* __restrict__ rowptr,
                                               int* __restrict__ rowptr_work,
                                               const int* __restrict__ bsum,
                                               const int* __restrict__ total, int n) {
    int b = blockIdx.x;
    int i0 = b * 1024 + threadIdx.x * 4;
    int add = bsum[b];
    #pragma unroll
    for (int j = 0; j < 4; ++j) {
        int i = i0 + j;
        if (i < n) {
            int v = rowptr[i] + add;
            rowptr[i] = v;
            rowptr_work[i] = v;
        }
    }
    if (b == 0 && threadIdx.x == 0) rowptr[n] = *total;
}

// ================= fat kernel: gemm3(LDS-W) || sqsk2 || scatter =================

__global__ __launch_bounds__(256) void k_fat(
    const unsigned short* __restrict__ Xb, const unsigned short* __restrict__ Wpk,
    const unsigned short* __restrict__ qkf, unsigned short* __restrict__ XW,
    float* __restrict__ sq, float* __restrict__ sk, int n,
    int nb_gemm, int nb_sqsk,
    const int* __restrict__ esrc, const int* __restrict__ edst,
    const int* __restrict__ etp, int* __restrict__ rowptr_work,
    int* __restrict__ pe, int ne) {
    __shared__ unsigned short lds_w[32 * 64 * 8];   // one relation's packed W, 32 KB
    const int b = blockIdx.x, tid = threadIdx.x;
    const int wv = tid >> 6, lane = tid & 63;
    const int l15 = lane & 15, g = lane >> 4;
    const int ntiles = (n + 15) >> 4;

    if (b < nb_gemm) {
        // ---- gemm: block-shared relation, W staged in LDS ----
        const int r = b & 7;
        const int nslots = (nb_gemm >> 3) * 4;     // wave-slots per relation
        const int slot0 = (b >> 3) * 4 + wv;

        const unsigned short* wsrc = Wpk + (size_t)r * 32 * 64 * 8;
        #pragma unroll
        for (int i = 0; i < 8; ++i) {
            int idx = tid + i * 256;               // 0..2047 x 16B
            *(uint4*)(lds_w + idx * 8) = *(const uint4*)(wsrc + (size_t)idx * 8);
        }
        __syncthreads();

        for (int t = slot0; t < ntiles; t += nslots) {
            int row = t * 16 + l15;
            bool ok = row < n;
            int rowc = ok ? row : n - 1;
            const unsigned short* xrow = Xb + (size_t)rowc * CH + g * 8;
            short8 xf[4];
            #pragma unroll
            for (int ks = 0; ks < 4; ++ks) xf[ks] = *(const short8*)(xrow + ks * 32);
            unsigned short* orow = XW + ((size_t)r * n + row) * CH;
            #pragma unroll
            for (int ct = 0; ct < 8; ++ct) {
                f32x4 a = {0.f, 0.f, 0.f, 0.f};
                #pragma unroll
                for (int ks = 0; ks < 4; ++ks) {
                    short8 wf = *(const short8*)(lds_w + ((ct * 4 + ks) * 64 + lane) * 8);
                    a = __builtin_amdgcn_mfma_f32_16x16x32_bf16(wf, xf[ks], a, 0, 0, 0);
                }
                unsigned p01, p23;
                asm("v_cvt_pk_bf16_f32 %0, %1, %2" : "=v"(p01) : "v"(a[0]), "v"(a[1]));
                asm("v_cvt_pk_bf16_f32 %0, %1, %2" : "=v"(p23) : "v"(a[2]), "v"(a[3]));
                if (ok) *(uint2*)(orow + ct * 16 + g * 4) = make_uint2(p01, p23);
            }
        }
    } else if (b < nb_gemm + nb_sqsk) {
        // ---- sqsk2 ----
        const int t = (b - nb_gemm) * 4 + wv;
        if (t >= ntiles) return;
        short8 qf[4];
        #pragma unroll
        for (int ks = 0; ks < 4; ++ks)
            qf[ks] = *(const short8*)(qkf + (size_t)(ks * 64 + lane) * 8);
        int row = t * 16 + l15;
        bool ok = row < n;
        int rowc = ok ? row : n - 1;
        const unsigned short* xrow = Xb + (size_t)rowc * CH + g * 8;
        short8 xf[4];
        #pragma unroll
        for (int ks = 0; ks < 4; ++ks) xf[ks] = *(const short8*)(xrow + ks * 32);
        f32x4 dq = {0.f, 0.f, 0.f, 0.f};
        #pragma unroll
        for (int ks = 0; ks < 4; ++ks)
            dq = __builtin_amdgcn_mfma_f32_16x16x32_bf16(qf[ks], xf[ks], dq, 0, 0, 0);
        if (ok) {
            float* base = (g < 2) ? sq : sk;
            int j0 = (g & 1) * 4;
            #pragma unroll
            for (int reg = 0; reg < 4; ++reg)
                base[(size_t)(j0 + reg) * n + row] = dq[reg];
        }
    } else {
        // ---- scatter ----
        int e = (b - nb_gemm - nb_sqsk) * 256 + tid;
        if (e >= ne) return;
        int pos = atomicAdd(rowptr_work + edst[e], 1);
        pe[pos] = (esrc[e] & 0xffff) | (etp[e] << 16);
    }
}

// ================= attn (+ optional next-layer wqk) =================

__global__ __launch_bounds__(256) void k_attn_wqk(
    const int* __restrict__ rowptr, const int* __restrict__ pe,
    const float* __restrict__ sq, const float* __restrict__ sk,
    const unsigned short* __restrict__ XW, const float* __restrict__ bias,
    unsigned short* __restrict__ outb, int n_nodes,
    const float* __restrict__ Wn, const float* __restrict__ qn,
    const float* __restrict__ kn, float* __restrict__ wqn,
    float* __restrict__ wkn, int nb_wqk) {
    int b = blockIdx.x;
    if (b < nb_wqk) { dev_wqk(Wn, qn, kn, wqn, wkn, b, threadIdx.x); return; }
    int wid = ((b - nb_wqk) * 256 + threadIdx.x) >> 6;
    int lane = threadIdx.x & 63;
    if (wid >= n_nodes) return;
    const int l16 = lane & 15, g16 = lane >> 4;
    int r0 = rowptr[wid], r1 = rowptr[wid + 1];
    float acc[8] = {};
    float denom = 0.f;

    if (r1 > r0) {
        float sqv = (lane < N_REL) ? sq[lane * n_nodes + wid] : 0.f;

        float m = -1e30f;
        for (int c0 = r0; c0 < r1; c0 += 64) {
            int j = c0 + lane;
            float a = -1e30f;
            if (j < r1) {
                int p = pe[j];
                int s = p & 0xffff, t = p >> 16;
                float av = __shfl(sqv, t) + sk[t * n_nodes + s];
                a = av >= 0.f ? av : NEG_SLOPE * av;
            }
            m = fmaxf(m, a);
        }
        #pragma unroll
        for (int off = 32; off; off >>= 1) m = fmaxf(m, __shfl_xor(m, off));

        for (int c0 = r0; c0 < r1; c0 += 64) {
            int j = c0 + lane;
            float ev = 0.f;
            int p = 0;
            if (j < r1) {
                p = pe[j];
                int s = p & 0xffff, t = p >> 16;
                float av = __shfl(sqv, t) + sk[t * n_nodes + s];
                av = av >= 0.f ? av : NEG_SLOPE * av;
                ev = __expf(av - m);
            }
            float evs = ev;
            #pragma unroll
            for (int off = 32; off; off >>= 1) evs += __shfl_xor(evs, off);
            denom += evs;

            int C = r1 - c0;
            if (C > 64) C = 64;
            for (int jj = 0; jj < C; jj += 4) {
                int lsel = jj + g16;
                float evj = __shfl(ev, lsel);
                int pj = __shfl(p, lsel);
                int s = pj & 0xffff, t = pj >> 16;
                const unsigned short* row = XW + ((size_t)(t * n_nodes + s)) * CH + l16 * 8;
                uint4 v = *(const uint4*)row;
                acc[0] += evj * __uint_as_float(v.x << 16);
                acc[1] += evj * __uint_as_float(v.x & 0xffff0000u);
                acc[2] += evj * __uint_as_float(v.y << 16);
                acc[3] += evj * __uint_as_float(v.y & 0xffff0000u);
                acc[4] += evj * __uint_as_float(v.z << 16);
                acc[5] += evj * __uint_as_float(v.z & 0xffff0000u);
                acc[6] += evj * __uint_as_float(v.w << 16);
                acc[7] += evj * __uint_as_float(v.w & 0xffff0000u);
            }
        }
    }

    #pragma unroll
    for (int i = 0; i < 8; ++i) {
        acc[i] += __shfl_xor(acc[i], 16);
        acc[i] += __shfl_xor(acc[i], 32);
    }

    if (lane < 16) {
        float inv = denom > 0.f ? 1.f / denom : 0.f;
        unsigned pk[4];
        #pragma unroll
        for (int i = 0; i < 4; ++i) {
            float b0 = bias[l16 * 8 + 2 * i];
            float b1 = bias[l16 * 8 + 2 * i + 1];
            float o0 = acc[2 * i] * inv + b0;
            float o1 = acc[2 * i + 1] * inv + b1;
            o0 = o0 > 0.f ? o0 : 0.f;
            o1 = o1 > 0.f ? o1 : 0.f;
            pk[i] = (unsigned)f2bf(o0) | ((unsigned)f2bf(o1) << 16);
        }
        *(uint4*)(outb + (size_t)wid * CH + l16 * 8) = make_uint4(pk[0], pk[1], pk[2], pk[3]);
    }
}

// ================= layer-2 W prep (wpack || qkpack) =================

__global__ __launch_bounds__(256) void k_wprep2(const float* __restrict__ W,
                                                unsigned short* __restrict__ Wpk,
                                                const float* __restrict__ wq,
                                                const float* __restrict__ wk,
                                                unsigned short* __restrict__ qkf) {
    int b = blockIdx.x, tid = threadIdx.x;
    if (b < 64) dev_wpack(W, Wpk, b * 256 + tid);
    else dev_qkpack(wq, wk, qkf, tid);
}

// ================= tail =================

__global__ __launch_bounds__(256) void k_colsum(const unsigned short* __restrict__ h,
                                                float* __restrict__ sum, int n_nodes) {
    __shared__ float cs[CH];
    int tid = threadIdx.x;
    int c2 = (tid & 63) * 2;
    int rw = tid >> 6;
    if (tid < CH) cs[tid] = 0.f;
    __syncthreads();
    float a0 = 0.f, a1 = 0.f;
    for (int row = blockIdx.x * 4 + rw; row < n_nodes; row += gridDim.x * 4) {
        unsigned v = *(const unsigned*)(h + (size_t)row * CH + c2);
        a0 += __uint_as_float(v << 16);
        a1 += __uint_as_float(v & 0xffff0000u);
    }
    atomicAdd(&cs[c2], a0);
    atomicAdd(&cs[c2 + 1], a1);
    __syncthreads();
    if (tid < CH) atomicAdd(sum + tid, cs[tid]);
}

__global__ void k_head(const float* __restrict__ sum, const float* __restrict__ lw,
                       const float* __restrict__ lb, float* __restrict__ outp, int n_nodes) {
    __shared__ float mean[CH];
    int t = threadIdx.x;  // 128
    mean[t] = sum[t] / (float)n_nodes;
    __syncthreads();
    if (t < OUT_CH) {
        float g = lb[t];
        for (int i = 0; i < CH; ++i) g += mean[i] * lw[i * OUT_CH + t];
        float m = g;
        #pragma unroll
        for (int off = 8; off; off >>= 1) m = fmaxf(m, __shfl_xor(m, off, 16));
        float ex = expf(g - m);
        float se = ex;
        #pragma unroll
        for (int off = 8; off; off >>= 1) se += __shfl_xor(se, off, 16);
        outp[t] = g - m - logf(se);
    }
}

extern "C" void kernel_launch(void* const* d_in, const int* in_sizes, int n_in,
                              void* d_out, int out_size, void* d_ws, size_t ws_size,
                              hipStream_t stream) {
    const float* x  = (const float*)d_in[0];
    const float* W1 = (const float*)d_in[1];
    const float* q1 = (const float*)d_in[2];
    const float* k1 = (const float*)d_in[3];
    const float* b1 = (const float*)d_in[4];
    const float* W2 = (const float*)d_in[5];
    const float* q2 = (const float*)d_in[6];
    const float* k2 = (const float*)d_in[7];
    const float* b2 = (const float*)d_in[8];
    const float* lw = (const float*)d_in[9];
    const float* lb = (const float*)d_in[10];
    const int* ei   = (const int*)d_in[11];
    const int* etp  = (const int*)d_in[12];

    const int n  = in_sizes[0] / CH;
    const int ne = in_sizes[12];
    const int* esrc = ei;
    const int* edst = ei + ne;

    char* ws = (char*)d_ws;
    size_t off = 0;
    auto carve = [&](size_t bytes) -> char* {
        char* p = ws + off;
        off = (off + bytes + 255) & ~(size_t)255;
        return p;
    };
    unsigned short* xw  = (unsigned short*)carve((size_t)N_REL * n * CH * 2);
    unsigned short* xb  = (unsigned short*)carve((size_t)n * CH * 2);
    unsigned short* h1b = (unsigned short*)carve((size_t)n * CH * 2);
    unsigned short* h2b = (unsigned short*)carve((size_t)n * CH * 2);
    unsigned short* wpk = (unsigned short*)carve((size_t)N_REL * 32 * 64 * 8 * 2);
    unsigned short* qkf = (unsigned short*)carve((size_t)256 * 8 * 2);
    float* sq     = (float*)carve((size_t)N_REL * n * 4);
    float* sk     = (float*)carve((size_t)N_REL * n * 4);
    float* wq     = (float*)carve(N_REL * CH * 4);
    float* wk     = (float*)carve(N_REL * CH * 4);
    int* count    = (int*)carve((size_t)n * 4);
    int* rowptr   = (int*)carve((size_t)(n + 1) * 4);
    int* rowptr_w = (int*)carve((size_t)n * 4);
    int* pe       = (int*)carve((size_t)ne * 4);
    int* bsum     = (int*)carve((size_t)256 * 4);
    int* total    = (int*)carve(4);
    float* sum128 = (float*)carve(CH * 4);

    hipMemsetAsync(count, 0, (size_t)n * 4, stream);
    hipMemsetAsync(sum128, 0, CH * 4, stream);

    const int nbscan = (n + 1023) / 1024;
    const int nb_cast = (int)(((long)n * CH / 8 + 255) / 256);
    const int nb_hist = (ne + 255) / 256;
    const int nb_gemm = 512;                          // 64 blocks x 8 relations
    const int ntiles = (n + 15) >> 4;
    const int nb_sqsk = (ntiles + 3) / 4;             // 782
    const int nb_scat = (ne + 255) / 256;             // 2344
    const int nb_attn = (n + 3) / 4;                  // 12500

    // cast || hist
    k_cast_hist<<<nb_cast + nb_hist, 256, 0, stream>>>(x, xb, (long)n * CH, edst, count, ne, nb_cast);
    // scan1 || wqk(L1)
    k_scan1_wqk<<<nbscan + 4, 256, 0, stream>>>(count, rowptr, bsum, n, nbscan, W1, q1, k1, wq, wk);
    // scan2 || wpack(L1) || qkpack(L1)
    k_scan2_wprep<<<66, 256, 0, stream>>>(bsum, total, nbscan, W1, wpk, wq, wk, qkf);
    k_scan3<<<nbscan, 256, 0, stream>>>(rowptr, rowptr_w, bsum, total, n);
    // layer 1: gemm || sqsk || scatter
    k_fat<<<nb_gemm + nb_sqsk + nb_scat, 256, 0, stream>>>(xb, wpk, qkf, xw, sq, sk, n,
                                                           nb_gemm, nb_sqsk,
                                                           esrc, edst, etp, rowptr_w, pe, ne);
    // attn(L1) || wqk(L2)
    k_attn_wqk<<<4 + nb_attn, 256, 0, stream>>>(rowptr, pe, sq, sk, xw, b1, h1b, n,
                                                W2, q2, k2, wq, wk, 4);
    // wpack(L2) || qkpack(L2)
    k_wprep2<<<65, 256, 0, stream>>>(W2, wpk, wq, wk, qkf);
    // layer 2: gemm || sqsk (no scatter)
    k_fat<<<nb_gemm + nb_sqsk, 256, 0, stream>>>(h1b, wpk, qkf, xw, sq, sk, n,
                                                 nb_gemm, nb_sqsk,
                                                 esrc, edst, etp, rowptr_w, pe, 0);
    // attn(L2)
    k_attn_wqk<<<nb_attn, 256, 0, stream>>>(rowptr, pe, sq, sk, xw, b2, h2b, n,
                                            (const float*)nullptr, (const float*)nullptr,
                                            (const float*)nullptr, (float*)nullptr,
                                            (float*)nullptr, 0);

    k_colsum<<<256, 256, 0, stream>>>(h2b, sum128, n);
    k_head<<<1, CH, 0, stream>>>(sum128, lw, lb, (float*)d_out, n);
}